// Round 9
// baseline (1811.407 us; speedup 1.0000x reference)
//
#include <hip/hip_runtime.h>
#include <hip/hip_bf16.h>

// Problem constants (fixed by the reference)
#define D 128        // feature dim
#define NLAYER 3
#define NCH 4

typedef __attribute__((ext_vector_type(8))) short short8;
typedef __attribute__((ext_vector_type(4))) float f32x4;

__device__ __forceinline__ ushort f2bf(float f) {
    unsigned int u = __builtin_bit_cast(unsigned int, f);
    u += 0x7fffu + ((u >> 16) & 1u);     // RNE
    return (ushort)(u >> 16);
}
__device__ __forceinline__ float bflo(unsigned int u) {
    return __builtin_bit_cast(float, u << 16);
}
__device__ __forceinline__ float bfhi(unsigned int u) {
    return __builtin_bit_cast(float, u & 0xffff0000u);
}

// ---------------------------------------------------------------------------
// CSR construction. hist and fill are XCD-partitioned: class = bid & 7 owns
// one contiguous eighth of dst-space (random 4B atomics stay in one XCD L2).
// ---------------------------------------------------------------------------
#define FILL_CHUNK 4096
__global__ __launch_bounds__(256) void hist_part_kernel(
    const int* __restrict__ dst, int* __restrict__ deg,
    int E, int nPer, int N)
{
    int cls = blockIdx.x & 7;
    int base = (blockIdx.x >> 3) * FILL_CHUNK;
    int lo = cls * nPer;
    int hi = lo + nPer; if (hi > N) hi = N;
    int end = base + FILL_CHUNK; if (end > E) end = E;
    for (int e = base + threadIdx.x; e < end; e += 256) {
        int d = dst[e];
        if (d >= lo && d < hi) atomicAdd(&deg[d], 1);
    }
}

__global__ __launch_bounds__(256) void blocksum_kernel(
    const int* __restrict__ deg, int* __restrict__ bsum, int n)
{
    int i = blockIdx.x * 256 + threadIdx.x;
    int v = (i < n) ? deg[i] : 0;
#pragma unroll
    for (int o = 1; o < 64; o <<= 1) v += __shfl_xor(v, o);
    __shared__ int s[4];
    if ((threadIdx.x & 63) == 0) s[threadIdx.x >> 6] = v;
    __syncthreads();
    if (threadIdx.x == 0) bsum[blockIdx.x] = s[0] + s[1] + s[2] + s[3];
}

__global__ __launch_bounds__(512) void scanblk_kernel(
    const int* __restrict__ bsum, int* __restrict__ boff, int nb,
    int* __restrict__ offs, int n, int E)
{
    __shared__ int sh[512];
    int t = threadIdx.x;
    sh[t] = (t < nb) ? bsum[t] : 0;
    __syncthreads();
    for (int d = 1; d < 512; d <<= 1) {
        int v = (t >= d) ? sh[t - d] : 0;
        __syncthreads();
        sh[t] += v;
        __syncthreads();
    }
    if (t < nb) boff[t] = (t == 0) ? 0 : sh[t - 1];
    if (t == 0) offs[n] = E;
}

__global__ __launch_bounds__(256) void blockscan_kernel(
    const int* __restrict__ deg, const int* __restrict__ boff,
    int* __restrict__ offs, int* __restrict__ cursor, int n)
{
    __shared__ int sh[256];
    int t = threadIdx.x;
    int i = blockIdx.x * 256 + t;
    int v = (i < n) ? deg[i] : 0;
    sh[t] = v;
    __syncthreads();
    for (int d = 1; d < 256; d <<= 1) {
        int u = (t >= d) ? sh[t - d] : 0;
        __syncthreads();
        sh[t] += u;
        __syncthreads();
    }
    if (i < n) {
        int ex = boff[blockIdx.x] + sh[t] - v;
        offs[i] = ex; cursor[i] = ex;
    }
}

__global__ __launch_bounds__(256) void fill_part_kernel(
    const int* __restrict__ src, const int* __restrict__ dst,
    int* __restrict__ cursor, int* __restrict__ csr,
    int E, int nPer, int N)
{
    int cls = blockIdx.x & 7;
    int base = (blockIdx.x >> 3) * FILL_CHUNK;
    int lo = cls * nPer;
    int hi = lo + nPer; if (hi > N) hi = N;
    int end = base + FILL_CHUNK; if (end > E) end = E;
    for (int e = base + threadIdx.x; e < end; e += 256) {
        int d = dst[e];
        int s = src[e];
        if (d >= lo && d < hi) {
            int p = atomicAdd(&cursor[d], 1);
            csr[p] = s;
        }
    }
}

// ---------------------------------------------------------------------------
// fp32 -> bf16 bulk convert (8 elems/thread)
// ---------------------------------------------------------------------------
__global__ __launch_bounds__(256) void cvtx_kernel(
    const float* __restrict__ x, ushort* __restrict__ xb, int total8)
{
    int i = blockIdx.x * 256 + threadIdx.x;
    if (i >= total8) return;
    const float* gp = x + (size_t)i * 8;
    float4 v0 = *(const float4*)gp;
    float4 v1 = *(const float4*)(gp + 4);
    short8 pk;
    pk[0] = (short)f2bf(v0.x); pk[1] = (short)f2bf(v0.y);
    pk[2] = (short)f2bf(v0.z); pk[3] = (short)f2bf(v0.w);
    pk[4] = (short)f2bf(v1.x); pk[5] = (short)f2bf(v1.y);
    pk[6] = (short)f2bf(v1.z); pk[7] = (short)f2bf(v1.w);
    *(short8*)(xb + (size_t)i * 8) = pk;
}

// ---------------------------------------------------------------------------
// Weight transpose + fp32->bf16: Wt[c][n][k] = bf16(W[c][k][n])
// ---------------------------------------------------------------------------
__global__ void cvtW_kernel(const float* __restrict__ W, ushort* __restrict__ Wt,
                            int K, int Ncols) {
    __shared__ float tile[32][33];
    int c = blockIdx.z;
    int k0 = blockIdx.x * 32, n0 = blockIdx.y * 32;
    const float* Wc = W + (size_t)c * K * Ncols;
    ushort* Wtc = Wt + (size_t)c * K * Ncols;
    int tx = threadIdx.x & 31, ty = threadIdx.x >> 5;
#pragma unroll
    for (int i = 0; i < 4; ++i) {
        int k = k0 + ty + i * 8;
        tile[ty + i * 8][tx] = Wc[(size_t)k * Ncols + n0 + tx];
    }
    __syncthreads();
#pragma unroll
    for (int i = 0; i < 4; ++i) {
        int n = n0 + ty + i * 8;
        Wtc[(size_t)n * K + k0 + tx] = f2bf(tile[tx][ty + i * 8]);
    }
}

// ---------------------------------------------------------------------------
// Fused GIN layer: gather-aggregate + 3-linear MLP in one kernel.
//   agg[r] = prev[r] + sum_{j in N(r)} prev[src_j]   (fp32 acc, f2bf -> As)
//   Out = relu(relu(relu(agg@W0+b0)@W1+b1)@W2+b2)    (bf16 MFMA, LDS roundtrip)
// Gather summation order and rounding points are bit-identical to the old
// separate agg_bf16 + gin_mlp_mfma pair -> absmax unchanged.
// Block = 128 rows, 256 threads, LDS 64 KB -> 2 blocks/CU.
// ---------------------------------------------------------------------------
__global__ __launch_bounds__(256) void gin_layer_mfma(
    const ushort* __restrict__ prev,   // [N,128] bf16 (gather source)
    const int* __restrict__ offs, const int* __restrict__ csr,
    const ushort* __restrict__ WtL,    // [3][128][128] bf16, n-major
    const float* __restrict__ biasL,   // [3][128]
    ushort* __restrict__ Out,          // [N,128] bf16
    int N)
{
    __shared__ __align__(16) ushort As[128 * 128];   // 32 KB
    __shared__ __align__(16) ushort Bs[128 * 128];   // 32 KB
    const int t = threadIdx.x;
    const int w = t >> 6, lane = t & 63;
    const int quad = lane >> 4, c15 = lane & 15;
    const int wr = w >> 1, wc = w & 1;
    const int rowbase = blockIdx.x * 128;

    // stage B0 first so the loads are in flight during the gather
#pragma unroll
    for (int i = 0; i < 8; ++i) {
        int lin = (i * 4 + w) * 64 + lane;
        int n = lin >> 4, slot = lin & 15, g = slot ^ (n & 15);
        const ushort* gp = WtL + (size_t)n * 128 + g * 8;
        __builtin_amdgcn_global_load_lds(
            (const __attribute__((address_space(1))) void*)gp,
            (__attribute__((address_space(3))) void*)&Bs[(i * 4 + w) * 512],
            16, 0, 0);
    }

    // gather prologue: wave w owns rows w*32 .. w*32+31; lane holds uint
    // (2 bf16) column pair. Same unroll-4 summation order as old agg_bf16.
    {
        const unsigned int* hb = (const unsigned int*)prev;
        unsigned int* Asw = (unsigned int*)As;
        const int gidx = (lane >> 2);        // granule 0..15
        const int sub = (lane & 3);          // uint within 16B granule
        for (int rr = 0; rr < 32; ++rr) {
            int row = w * 32 + rr;
            int node = rowbase + row;
            float ax = 0.f, ay = 0.f;
            if (node < N) {
                unsigned int u = hb[(size_t)node * 64 + lane];
                ax = bflo(u); ay = bfhi(u);
                int b = offs[node], e = offs[node + 1];
                int j = b;
                for (; j + 4 <= e; j += 4) {
                    int s0 = csr[j], s1 = csr[j + 1], s2 = csr[j + 2], s3 = csr[j + 3];
                    unsigned int u0 = hb[(size_t)s0 * 64 + lane];
                    unsigned int u1 = hb[(size_t)s1 * 64 + lane];
                    unsigned int u2 = hb[(size_t)s2 * 64 + lane];
                    unsigned int u3 = hb[(size_t)s3 * 64 + lane];
                    ax += (bflo(u0) + bflo(u1)) + (bflo(u2) + bflo(u3));
                    ay += (bfhi(u0) + bfhi(u1)) + (bfhi(u2) + bfhi(u3));
                }
                for (; j < e; ++j) {
                    unsigned int u0 = hb[(size_t)csr[j] * 64 + lane];
                    ax += bflo(u0); ay += bfhi(u0);
                }
            }
            unsigned int po = (unsigned int)f2bf(ax) | ((unsigned int)f2bf(ay) << 16);
            Asw[row * 64 + ((gidx ^ (row & 15)) * 4) + sub] = po;
        }
    }
    __syncthreads();

    for (int s = 0; s < 3; ++s) {
        f32x4 acc[4][4];
#pragma unroll
        for (int i = 0; i < 4; ++i)
#pragma unroll
            for (int j = 0; j < 4; ++j)
#pragma unroll
                for (int r = 0; r < 4; ++r) acc[i][j][r] = 0.f;

#pragma unroll
        for (int ks = 0; ks < 4; ++ks) {
            short8 af[4], bf[4];
#pragma unroll
            for (int tr = 0; tr < 4; ++tr) {
                int r = wr * 64 + tr * 16 + c15;
                af[tr] = *(const short8*)&As[r * 128 + (((ks * 4 + quad) ^ (r & 15)) * 8)];
            }
#pragma unroll
            for (int tc = 0; tc < 4; ++tc) {
                int n = wc * 64 + tc * 16 + c15;
                bf[tc] = *(const short8*)&Bs[n * 128 + (((ks * 4 + quad) ^ (n & 15)) * 8)];
            }
#pragma unroll
            for (int tr = 0; tr < 4; ++tr)
#pragma unroll
                for (int tc = 0; tc < 4; ++tc)
                    acc[tr][tc] = __builtin_amdgcn_mfma_f32_16x16x32_bf16(
                        af[tr], bf[tc], acc[tr][tc], 0, 0, 0);
        }
        __syncthreads();

        if (s < 2) {
#pragma unroll
            for (int tc = 0; tc < 4; ++tc) {
                int col = wc * 64 + tc * 16 + c15;
                float bv = biasL[s * 128 + col];
#pragma unroll
                for (int tr = 0; tr < 4; ++tr)
#pragma unroll
                    for (int rg = 0; rg < 4; ++rg) {
                        int row = wr * 64 + tr * 16 + quad * 4 + rg;
                        As[row * 128 + (((col >> 3) ^ (row & 15)) * 8) + (col & 7)]
                            = f2bf(fmaxf(acc[tr][tc][rg] + bv, 0.f));
                    }
            }
            const ushort* Wn = WtL + (size_t)(s + 1) * 128 * 128;
#pragma unroll
            for (int i = 0; i < 8; ++i) {
                int lin = (i * 4 + w) * 64 + lane;
                int n = lin >> 4, slot = lin & 15, g = slot ^ (n & 15);
                const ushort* gp = Wn + (size_t)n * 128 + g * 8;
                __builtin_amdgcn_global_load_lds(
                    (const __attribute__((address_space(1))) void*)gp,
                    (__attribute__((address_space(3))) void*)&Bs[(i * 4 + w) * 512],
                    16, 0, 0);
            }
            __syncthreads();
        } else {
#pragma unroll
            for (int tc = 0; tc < 4; ++tc) {
                int col = wc * 64 + tc * 16 + c15;
                float bv = biasL[2 * 128 + col];
#pragma unroll
                for (int tr = 0; tr < 4; ++tr)
#pragma unroll
                    for (int rg = 0; rg < 4; ++rg) {
                        int grow = rowbase + wr * 64 + tr * 16 + quad * 4 + rg;
                        if (grow < N)
                            Out[(size_t)grow * 128 + col]
                                = f2bf(fmaxf(acc[tr][tc][rg] + bv, 0.f));
                    }
            }
        }
    }
}

// ---------------------------------------------------------------------------
// Fully fused channel MLP (unchanged from R8: 64-row/256-thread, 2 blocks/CU,
// XCD-aware swizzle: xcd = bid & 7 owns a contiguous chunk of row tiles).
// ---------------------------------------------------------------------------
__global__ __launch_bounds__(256, 2) void chan_fused_mfma(
    const ushort* __restrict__ A0, const ushort* __restrict__ A1,
    const ushort* __restrict__ A2, const ushort* __restrict__ A3,
    const ushort* __restrict__ Wt1,    // [NCH*256][512] bf16 n-major
    const float* __restrict__ b1,      // [NCH*256]
    const ushort* __restrict__ Wt2,    // [NCH][256][256] bf16 n-major
    const float* __restrict__ b2,      // [NCH*256]
    const float* __restrict__ w3,      // [NCH*256]
    const float* __restrict__ b3,      // [NCH]
    float* __restrict__ out,           // [N, NCH]
    int N, int T, int chunkT)
{
    const int bid = blockIdx.x;
    const int xcd = bid & 7;
    const int idx = bid >> 3;
    const int c = idx & 3;
    const int rt = xcd * chunkT + (idx >> 2);
    if (rt >= T) return;
    const int rowbase = rt * 64;

    __shared__ __align__(16) ushort As[64 * 64];     //  8 KB
    __shared__ __align__(16) ushort Bs[256 * 64];    // 32 KB
    __shared__ __align__(16) ushort Ts[64 * 256];    // 32 KB
    __shared__ float red[64][4];
    const int t = threadIdx.x;
    const int w = t >> 6, lane = t & 63;
    const int quad = lane >> 4, c15 = lane & 15;
    const ushort* Asrc[4] = {A0, A1, A2, A3};
    const ushort* W1c = Wt1 + (size_t)c * 256 * 512;
    const ushort* W2c = Wt2 + (size_t)c * 256 * 256;

    f32x4 acc[4][4];
#pragma unroll
    for (int i = 0; i < 4; ++i)
#pragma unroll
        for (int j = 0; j < 4; ++j)
#pragma unroll
            for (int r = 0; r < 4; ++r) acc[i][j][r] = 0.f;

    // ---- Phase 1: L1 GEMM, K = 512 over the 4 virtual-concat slices ----
    for (int kc = 0; kc < 512; kc += 64) {
        const ushort* Ab = Asrc[kc >> 7];
        const int within = kc & 127;
#pragma unroll
        for (int i = 0; i < 2; ++i) {
            int lin = (i * 4 + w) * 64 + lane;
            int row = lin >> 3, slot = lin & 7, g = slot ^ (row & 7);
            int grow = rowbase + row;
            if (grow >= N) grow = 0;
            const ushort* gp = Ab + (size_t)grow * 128 + within + g * 8;
            __builtin_amdgcn_global_load_lds(
                (const __attribute__((address_space(1))) void*)gp,
                (__attribute__((address_space(3))) void*)&As[(i * 4 + w) * 512],
                16, 0, 0);
        }
#pragma unroll
        for (int i = 0; i < 8; ++i) {
            int lin = (i * 4 + w) * 64 + lane;
            int n = lin >> 3, slot = lin & 7, g = slot ^ (n & 7);
            const ushort* gp = W1c + (size_t)n * 512 + kc + g * 8;
            __builtin_amdgcn_global_load_lds(
                (const __attribute__((address_space(1))) void*)gp,
                (__attribute__((address_space(3))) void*)&Bs[(i * 4 + w) * 512],
                16, 0, 0);
        }
        __syncthreads();
#pragma unroll
        for (int ks = 0; ks < 2; ++ks) {
            const int K8 = ks * 4;
            short8 af[4], bf[4];
#pragma unroll
            for (int tr = 0; tr < 4; ++tr) {
                int r = tr * 16 + c15;
                af[tr] = *(const short8*)&As[r * 64 + (((K8 + quad) ^ (r & 7)) * 8)];
            }
#pragma unroll
            for (int tc = 0; tc < 4; ++tc) {
                int n = w * 64 + tc * 16 + c15;
                bf[tc] = *(const short8*)&Bs[n * 64 + (((K8 + quad) ^ (n & 7)) * 8)];
            }
#pragma unroll
            for (int tr = 0; tr < 4; ++tr)
#pragma unroll
                for (int tc = 0; tc < 4; ++tc)
                    acc[tr][tc] = __builtin_amdgcn_mfma_f32_16x16x32_bf16(
                        af[tr], bf[tc], acc[tr][tc], 0, 0, 0);
        }
        __syncthreads();
    }

    // ---- T1 tile -> Ts (bf16, 32-granule XOR swizzle per row) ----
#pragma unroll
    for (int tc = 0; tc < 4; ++tc) {
        int col = w * 64 + tc * 16 + c15;
        float bv = b1[c * 256 + col];
#pragma unroll
        for (int tr = 0; tr < 4; ++tr)
#pragma unroll
            for (int rg = 0; rg < 4; ++rg) {
                int row = tr * 16 + quad * 4 + rg;
                Ts[row * 256 + (((col >> 3) ^ (row & 31)) * 8) + (col & 7)]
                    = f2bf(fmaxf(acc[tr][tc][rg] + bv, 0.f));
            }
    }
    __syncthreads();

    // ---- Phase 2: L2 GEMM, K = 256 from Ts ----
#pragma unroll
    for (int i = 0; i < 4; ++i)
#pragma unroll
        for (int j = 0; j < 4; ++j)
#pragma unroll
            for (int r = 0; r < 4; ++r) acc[i][j][r] = 0.f;

    for (int kc = 0; kc < 256; kc += 64) {
#pragma unroll
        for (int i = 0; i < 8; ++i) {
            int lin = (i * 4 + w) * 64 + lane;
            int n = lin >> 3, slot = lin & 7, g = slot ^ (n & 7);
            const ushort* gp = W2c + (size_t)n * 256 + kc + g * 8;
            __builtin_amdgcn_global_load_lds(
                (const __attribute__((address_space(1))) void*)gp,
                (__attribute__((address_space(3))) void*)&Bs[(i * 4 + w) * 512],
                16, 0, 0);
        }
        __syncthreads();
#pragma unroll
        for (int ks = 0; ks < 2; ++ks) {
            short8 af[4], bf[4];
            const int g0 = (kc >> 3) + ks * 4 + quad;
#pragma unroll
            for (int tr = 0; tr < 4; ++tr) {
                int r = tr * 16 + c15;
                af[tr] = *(const short8*)&Ts[r * 256 + ((g0 ^ (r & 31)) * 8)];
            }
#pragma unroll
            for (int tc = 0; tc < 4; ++tc) {
                int n = w * 64 + tc * 16 + c15;
                bf[tc] = *(const short8*)&Bs[n * 64 + ((((ks * 4) + quad) ^ (n & 7)) * 8)];
            }
#pragma unroll
            for (int tr = 0; tr < 4; ++tr)
#pragma unroll
                for (int tc = 0; tc < 4; ++tc)
                    acc[tr][tc] = __builtin_amdgcn_mfma_f32_16x16x32_bf16(
                        af[tr], bf[tc], acc[tr][tc], 0, 0, 0);
        }
        __syncthreads();
    }

    // ---- Phase 3: relu(acc+b2) dot w3 ----
    float b2v[4], w3v[4];
#pragma unroll
    for (int tc = 0; tc < 4; ++tc) {
        int col = w * 64 + tc * 16 + c15;
        b2v[tc] = b2[c * 256 + col];
        w3v[tc] = w3[c * 256 + col];
    }
#pragma unroll
    for (int tr = 0; tr < 4; ++tr)
#pragma unroll
        for (int rg = 0; rg < 4; ++rg) {
            float p = 0.f;
#pragma unroll
            for (int tc = 0; tc < 4; ++tc)
                p += fmaxf(acc[tr][tc][rg] + b2v[tc], 0.f) * w3v[tc];
            p += __shfl_xor(p, 1);
            p += __shfl_xor(p, 2);
            p += __shfl_xor(p, 4);
            p += __shfl_xor(p, 8);
            if (c15 == 0) red[tr * 16 + quad * 4 + rg][w] = p;
        }
    __syncthreads();
    if (t < 64) {
        int grow = rowbase + t;
        if (grow < N) {
            float s = red[t][0] + red[t][1] + red[t][2] + red[t][3] + b3[c];
            out[(size_t)grow * NCH + c] = fmaxf(s, 0.f);
        }
    }
}

// ---------------------------------------------------------------------------
// Launch
// ---------------------------------------------------------------------------
extern "C" void kernel_launch(void* const* d_in, const int* in_sizes, int n_in,
                              void* d_out, int out_size, void* d_ws, size_t ws_size,
                              hipStream_t stream) {
    const float* x        = (const float*)d_in[0];
    const int*   eidx     = (const int*)d_in[1];
    const float* convW    = (const float*)d_in[2];
    const float* convB    = (const float*)d_in[3];
    const float* chanW1   = (const float*)d_in[4];
    const float* chanB1   = (const float*)d_in[5];
    const float* chanW2   = (const float*)d_in[6];
    const float* chanB2   = (const float*)d_in[7];
    const float* chanW3   = (const float*)d_in[8];
    const float* chanB3   = (const float*)d_in[9];
    float* out = (float*)d_out;

    const int N = in_sizes[0] / D;      // 100000
    const int E = in_sizes[1] / 2;      // 1600000
    const int* srcp = eidx;
    const int* dstp = eidx + E;
    const int nb = (N + 255) / 256;     // 391

    char* w = (char*)d_ws;
    auto take = [&](size_t bytes) {
        char* p = w;
        w += (bytes + 255) & ~(size_t)255;
        return p;
    };
    ushort* xb     = (ushort*)take((size_t)N * D * 2);
    ushort* h0     = (ushort*)take((size_t)N * D * 2);
    ushort* h1     = (ushort*)take((size_t)N * D * 2);
    ushort* h2     = (ushort*)take((size_t)N * D * 2);
    int*    deg    = (int*)take((size_t)N * 4);
    int*    offs   = (int*)take((size_t)(N + 1) * 4);
    int*    cursor = (int*)take((size_t)N * 4);
    int*    bsum   = (int*)take((size_t)nb * 4);
    int*    boff   = (int*)take((size_t)nb * 4);
    ushort* Wt1b   = (ushort*)take((size_t)NCH * 256 * 512 * 2);
    ushort* Wt2b   = (ushort*)take((size_t)NCH * 256 * 256 * 2);
    ushort* WtC    = (ushort*)take((size_t)NLAYER * 3 * D * D * 2);

    size_t used = (size_t)(w - (char*)d_ws);
    if (used > ws_size) return;
    size_t rem = ws_size - used;
    if (rem < (size_t)E * 4) return;

    int* csr = (int*)w;

    // --- CSR build (XCD-partitioned hist + parallel scan + partitioned fill) ---
    hipMemsetAsync(deg, 0, (size_t)N * 4, stream);
    {
        int nchunks = (E + FILL_CHUNK - 1) / FILL_CHUNK;
        int nPer = (N + 7) / 8;
        hist_part_kernel<<<nchunks * 8, 256, 0, stream>>>(dstp, deg, E, nPer, N);
        blocksum_kernel<<<nb, 256, 0, stream>>>(deg, bsum, N);
        scanblk_kernel<<<1, 512, 0, stream>>>(bsum, boff, nb, offs, N, E);
        blockscan_kernel<<<nb, 256, 0, stream>>>(deg, boff, offs, cursor, N);
        fill_part_kernel<<<nchunks * 8, 256, 0, stream>>>(
            srcp, dstp, cursor, csr, E, nPer, N);
    }

    // --- converts (independent) ---
    cvtx_kernel<<<(N * 16 + 255) / 256, 256, 0, stream>>>(x, xb, N * 16);
    cvtW_kernel<<<dim3(512 / 32, 256 / 32, NCH), 256, 0, stream>>>(chanW1, Wt1b, 512, 256);
    cvtW_kernel<<<dim3(256 / 32, 256 / 32, NCH), 256, 0, stream>>>(chanW2, Wt2b, 256, 256);
    cvtW_kernel<<<dim3(D / 32, D / 32, NLAYER * 3), 256, 0, stream>>>(convW, WtC, D, D);

    const int rowtiles = (N + 127) / 128;

    // --- GIN layers: fused gather + 3-linear MLP per layer ---
    ushort* hbuf[NLAYER] = {h0, h1, h2};
    const ushort* prev = xb;
    for (int l = 0; l < NLAYER; ++l) {
        gin_layer_mfma<<<rowtiles, 256, 0, stream>>>(
            prev, offs, csr,
            WtC + (size_t)l * 3 * D * D, convB + (size_t)l * 3 * D, hbuf[l], N);
        prev = hbuf[l];
    }

    // --- channel MLPs: fused, 64-row tiles, XCD-aware swizzled grid ---
    {
        const int T = (N + 63) / 64;          // 1563 row tiles
        const int chunkT = (T + 7) / 8;       // row tiles per XCD class
        const int grid = 8 * chunkT * NCH;
        chan_fused_mfma<<<grid, 256, 0, stream>>>(
            xb, h0, h1, h2,
            Wt1b, chanB1, Wt2b, chanB2, chanW3, chanB3,
            out, N, T, chunkT);
    }
}

// Round 10
// 1320.105 us; speedup vs baseline: 1.3722x; 1.3722x over previous
//
#include <hip/hip_runtime.h>
#include <hip/hip_bf16.h>

// Problem constants (fixed by the reference)
#define D 128        // feature dim
#define NLAYER 3
#define NCH 4

typedef __attribute__((ext_vector_type(8))) short short8;
typedef __attribute__((ext_vector_type(4))) float f32x4;

__device__ __forceinline__ ushort f2bf(float f) {
    unsigned int u = __builtin_bit_cast(unsigned int, f);
    u += 0x7fffu + ((u >> 16) & 1u);     // RNE
    return (ushort)(u >> 16);
}
__device__ __forceinline__ float bflo(unsigned int u) {
    return __builtin_bit_cast(float, u << 16);
}
__device__ __forceinline__ float bfhi(unsigned int u) {
    return __builtin_bit_cast(float, u & 0xffff0000u);
}

// ---------------------------------------------------------------------------
// CSR construction. hist and fill are XCD-partitioned: class = bid & 7 owns
// one contiguous eighth of dst-space (random 4B atomics stay in one XCD L2).
// ---------------------------------------------------------------------------
#define FILL_CHUNK 4096
__global__ __launch_bounds__(256) void hist_part_kernel(
    const int* __restrict__ dst, int* __restrict__ deg,
    int E, int nPer, int N)
{
    int cls = blockIdx.x & 7;
    int base = (blockIdx.x >> 3) * FILL_CHUNK;
    int lo = cls * nPer;
    int hi = lo + nPer; if (hi > N) hi = N;
    int end = base + FILL_CHUNK; if (end > E) end = E;
    for (int e = base + threadIdx.x; e < end; e += 256) {
        int d = dst[e];
        if (d >= lo && d < hi) atomicAdd(&deg[d], 1);
    }
}

__global__ __launch_bounds__(256) void blocksum_kernel(
    const int* __restrict__ deg, int* __restrict__ bsum, int n)
{
    int i = blockIdx.x * 256 + threadIdx.x;
    int v = (i < n) ? deg[i] : 0;
#pragma unroll
    for (int o = 1; o < 64; o <<= 1) v += __shfl_xor(v, o);
    __shared__ int s[4];
    if ((threadIdx.x & 63) == 0) s[threadIdx.x >> 6] = v;
    __syncthreads();
    if (threadIdx.x == 0) bsum[blockIdx.x] = s[0] + s[1] + s[2] + s[3];
}

__global__ __launch_bounds__(512) void scanblk_kernel(
    const int* __restrict__ bsum, int* __restrict__ boff, int nb,
    int* __restrict__ offs, int n, int E)
{
    __shared__ int sh[512];
    int t = threadIdx.x;
    sh[t] = (t < nb) ? bsum[t] : 0;
    __syncthreads();
    for (int d = 1; d < 512; d <<= 1) {
        int v = (t >= d) ? sh[t - d] : 0;
        __syncthreads();
        sh[t] += v;
        __syncthreads();
    }
    if (t < nb) boff[t] = (t == 0) ? 0 : sh[t - 1];
    if (t == 0) offs[n] = E;
}

__global__ __launch_bounds__(256) void blockscan_kernel(
    const int* __restrict__ deg, const int* __restrict__ boff,
    int* __restrict__ offs, int* __restrict__ cursor, int n)
{
    __shared__ int sh[256];
    int t = threadIdx.x;
    int i = blockIdx.x * 256 + t;
    int v = (i < n) ? deg[i] : 0;
    sh[t] = v;
    __syncthreads();
    for (int d = 1; d < 256; d <<= 1) {
        int u = (t >= d) ? sh[t - d] : 0;
        __syncthreads();
        sh[t] += u;
        __syncthreads();
    }
    if (i < n) {
        int ex = boff[blockIdx.x] + sh[t] - v;
        offs[i] = ex; cursor[i] = ex;
    }
}

__global__ __launch_bounds__(256) void fill_part_kernel(
    const int* __restrict__ src, const int* __restrict__ dst,
    int* __restrict__ cursor, int* __restrict__ csr,
    int E, int nPer, int N)
{
    int cls = blockIdx.x & 7;
    int base = (blockIdx.x >> 3) * FILL_CHUNK;
    int lo = cls * nPer;
    int hi = lo + nPer; if (hi > N) hi = N;
    int end = base + FILL_CHUNK; if (end > E) end = E;
    for (int e = base + threadIdx.x; e < end; e += 256) {
        int d = dst[e];
        int s = src[e];
        if (d >= lo && d < hi) {
            int p = atomicAdd(&cursor[d], 1);
            csr[p] = s;
        }
    }
}

// ---------------------------------------------------------------------------
// fp32 -> bf16 bulk convert (8 elems/thread)
// ---------------------------------------------------------------------------
__global__ __launch_bounds__(256) void cvtx_kernel(
    const float* __restrict__ x, ushort* __restrict__ xb, int total8)
{
    int i = blockIdx.x * 256 + threadIdx.x;
    if (i >= total8) return;
    const float* gp = x + (size_t)i * 8;
    float4 v0 = *(const float4*)gp;
    float4 v1 = *(const float4*)(gp + 4);
    short8 pk;
    pk[0] = (short)f2bf(v0.x); pk[1] = (short)f2bf(v0.y);
    pk[2] = (short)f2bf(v0.z); pk[3] = (short)f2bf(v0.w);
    pk[4] = (short)f2bf(v1.x); pk[5] = (short)f2bf(v1.y);
    pk[6] = (short)f2bf(v1.z); pk[7] = (short)f2bf(v1.w);
    *(short8*)(xb + (size_t)i * 8) = pk;
}

// ---------------------------------------------------------------------------
// Weight transpose + fp32->bf16: Wt[c][n][k] = bf16(W[c][k][n])
// ---------------------------------------------------------------------------
__global__ void cvtW_kernel(const float* __restrict__ W, ushort* __restrict__ Wt,
                            int K, int Ncols) {
    __shared__ float tile[32][33];
    int c = blockIdx.z;
    int k0 = blockIdx.x * 32, n0 = blockIdx.y * 32;
    const float* Wc = W + (size_t)c * K * Ncols;
    ushort* Wtc = Wt + (size_t)c * K * Ncols;
    int tx = threadIdx.x & 31, ty = threadIdx.x >> 5;
#pragma unroll
    for (int i = 0; i < 4; ++i) {
        int k = k0 + ty + i * 8;
        tile[ty + i * 8][tx] = Wc[(size_t)k * Ncols + n0 + tx];
    }
    __syncthreads();
#pragma unroll
    for (int i = 0; i < 4; ++i) {
        int n = n0 + ty + i * 8;
        Wtc[(size_t)n * K + k0 + tx] = f2bf(tile[tx][ty + i * 8]);
    }
}

// ---------------------------------------------------------------------------
// Aggregation (bf16 in/out, fp32 accumulate), one wave per node (100k-wave
// TLP — do NOT fuse into the MLP kernel; R9 proved that collapses TLP 32x).
// ---------------------------------------------------------------------------
__global__ __launch_bounds__(256) void agg_bf16(
    const ushort* __restrict__ h,
    const int* __restrict__ offs, const int* __restrict__ csr,
    ushort* __restrict__ outb, int n)
{
    int wid = (blockIdx.x * 256 + threadIdx.x) >> 6;
    int lane = threadIdx.x & 63;
    if (wid >= n) return;
    const unsigned int* hb = (const unsigned int*)h;
    unsigned int u = hb[(size_t)wid * 64 + lane];
    float ax = bflo(u), ay = bfhi(u);
    int b = offs[wid], e = offs[wid + 1];
    int j = b;
    for (; j + 4 <= e; j += 4) {
        int s0 = csr[j], s1 = csr[j + 1], s2 = csr[j + 2], s3 = csr[j + 3];
        unsigned int u0 = hb[(size_t)s0 * 64 + lane];
        unsigned int u1 = hb[(size_t)s1 * 64 + lane];
        unsigned int u2 = hb[(size_t)s2 * 64 + lane];
        unsigned int u3 = hb[(size_t)s3 * 64 + lane];
        ax += (bflo(u0) + bflo(u1)) + (bflo(u2) + bflo(u3));
        ay += (bfhi(u0) + bfhi(u1)) + (bfhi(u2) + bfhi(u3));
    }
    for (; j < e; ++j) {
        unsigned int u0 = hb[(size_t)csr[j] * 64 + lane];
        ax += bflo(u0); ay += bfhi(u0);
    }
    unsigned int po = (unsigned int)f2bf(ax) | ((unsigned int)f2bf(ay) << 16);
    ((unsigned int*)outb)[(size_t)wid * 64 + lane] = po;
}

// ---------------------------------------------------------------------------
// Fused GIN-layer MLP: Out = relu(relu(relu(A@W0+b0)@W1+b1)@W2+b2)
// ---------------------------------------------------------------------------
__global__ __launch_bounds__(256) void gin_mlp_mfma(
    const ushort* __restrict__ A,
    const ushort* __restrict__ WtL,    // [3][128][128] bf16, n-major
    const float* __restrict__ biasL,   // [3][128]
    ushort* __restrict__ Out,
    int nrows)
{
    __shared__ __align__(16) ushort As[128 * 128];   // 32 KB
    __shared__ __align__(16) ushort Bs[128 * 128];   // 32 KB
    const int t = threadIdx.x;
    const int w = t >> 6, lane = t & 63;
    const int quad = lane >> 4, c15 = lane & 15;
    const int wr = w >> 1, wc = w & 1;
    const int rowbase = blockIdx.x * 128;

#pragma unroll
    for (int i = 0; i < 8; ++i) {
        int lin = (i * 4 + w) * 64 + lane;
        int row = lin >> 4, slot = lin & 15, g = slot ^ (row & 15);
        int grow = rowbase + row;
        if (grow >= nrows) grow = 0;
        const ushort* gp = A + (size_t)grow * 128 + g * 8;
        __builtin_amdgcn_global_load_lds(
            (const __attribute__((address_space(1))) void*)gp,
            (__attribute__((address_space(3))) void*)&As[(i * 4 + w) * 512],
            16, 0, 0);
    }
#pragma unroll
    for (int i = 0; i < 8; ++i) {
        int lin = (i * 4 + w) * 64 + lane;
        int n = lin >> 4, slot = lin & 15, g = slot ^ (n & 15);
        const ushort* gp = WtL + (size_t)n * 128 + g * 8;
        __builtin_amdgcn_global_load_lds(
            (const __attribute__((address_space(1))) void*)gp,
            (__attribute__((address_space(3))) void*)&Bs[(i * 4 + w) * 512],
            16, 0, 0);
    }
    __syncthreads();

    for (int s = 0; s < 3; ++s) {
        f32x4 acc[4][4];
#pragma unroll
        for (int i = 0; i < 4; ++i)
#pragma unroll
            for (int j = 0; j < 4; ++j)
#pragma unroll
                for (int r = 0; r < 4; ++r) acc[i][j][r] = 0.f;

#pragma unroll
        for (int ks = 0; ks < 4; ++ks) {
            short8 af[4], bf[4];
#pragma unroll
            for (int tr = 0; tr < 4; ++tr) {
                int r = wr * 64 + tr * 16 + c15;
                af[tr] = *(const short8*)&As[r * 128 + (((ks * 4 + quad) ^ (r & 15)) * 8)];
            }
#pragma unroll
            for (int tc = 0; tc < 4; ++tc) {
                int n = wc * 64 + tc * 16 + c15;
                bf[tc] = *(const short8*)&Bs[n * 128 + (((ks * 4 + quad) ^ (n & 15)) * 8)];
            }
#pragma unroll
            for (int tr = 0; tr < 4; ++tr)
#pragma unroll
                for (int tc = 0; tc < 4; ++tc)
                    acc[tr][tc] = __builtin_amdgcn_mfma_f32_16x16x32_bf16(
                        af[tr], bf[tc], acc[tr][tc], 0, 0, 0);
        }
        __syncthreads();

        if (s < 2) {
#pragma unroll
            for (int tc = 0; tc < 4; ++tc) {
                int col = wc * 64 + tc * 16 + c15;
                float bv = biasL[s * 128 + col];
#pragma unroll
                for (int tr = 0; tr < 4; ++tr)
#pragma unroll
                    for (int rg = 0; rg < 4; ++rg) {
                        int row = wr * 64 + tr * 16 + quad * 4 + rg;
                        As[row * 128 + (((col >> 3) ^ (row & 15)) * 8) + (col & 7)]
                            = f2bf(fmaxf(acc[tr][tc][rg] + bv, 0.f));
                    }
            }
            const ushort* Wn = WtL + (size_t)(s + 1) * 128 * 128;
#pragma unroll
            for (int i = 0; i < 8; ++i) {
                int lin = (i * 4 + w) * 64 + lane;
                int n = lin >> 4, slot = lin & 15, g = slot ^ (n & 15);
                const ushort* gp = Wn + (size_t)n * 128 + g * 8;
                __builtin_amdgcn_global_load_lds(
                    (const __attribute__((address_space(1))) void*)gp,
                    (__attribute__((address_space(3))) void*)&Bs[(i * 4 + w) * 512],
                    16, 0, 0);
            }
            __syncthreads();
        } else {
#pragma unroll
            for (int tc = 0; tc < 4; ++tc) {
                int col = wc * 64 + tc * 16 + c15;
                float bv = biasL[2 * 128 + col];
#pragma unroll
                for (int tr = 0; tr < 4; ++tr)
#pragma unroll
                    for (int rg = 0; rg < 4; ++rg) {
                        int grow = rowbase + wr * 64 + tr * 16 + quad * 4 + rg;
                        if (grow < nrows)
                            Out[(size_t)grow * 128 + col]
                                = f2bf(fmaxf(acc[tr][tc][rg] + bv, 0.f));
                    }
            }
        }
    }
}

// ---------------------------------------------------------------------------
// Fully fused channel MLP v3: 128 rows (two 64-row halves) x 1 channel per
// block, 256 threads, 2 blocks/CU. Each W1 k-chunk is staged ONCE and used by
// both halves (halves W1 L2->LDS traffic, the co-limiting term at R8's
// 240 us). Per-element accumulation order identical to R8 -> absmax 0.25.
// XCD-aware swizzle retained (xcd = bid & 7 owns contiguous row-tile chunk).
// LDS: As 8K + Bs 32K + Ts 32K + red 1K = 73 KB.
// ---------------------------------------------------------------------------
__global__ __launch_bounds__(256, 2) void chan_fused_mfma(
    const ushort* __restrict__ A0, const ushort* __restrict__ A1,
    const ushort* __restrict__ A2, const ushort* __restrict__ A3,
    const ushort* __restrict__ Wt1,    // [NCH*256][512] bf16 n-major
    const float* __restrict__ b1,      // [NCH*256]
    const ushort* __restrict__ Wt2,    // [NCH][256][256] bf16 n-major
    const float* __restrict__ b2,      // [NCH*256]
    const float* __restrict__ w3,      // [NCH*256]
    const float* __restrict__ b3,      // [NCH]
    float* __restrict__ out,           // [N, NCH]
    int N, int T, int chunkT)
{
    const int bid = blockIdx.x;
    const int xcd = bid & 7;
    const int idx = bid >> 3;
    const int c = idx & 3;
    const int rt = xcd * chunkT + (idx >> 2);
    if (rt >= T) return;
    const int rowbaseA = rt * 128;
    const int rowbaseB = rowbaseA + 64;

    __shared__ __align__(16) ushort As[64 * 64];     //  8 KB
    __shared__ __align__(16) ushort Bs[256 * 64];    // 32 KB
    __shared__ __align__(16) ushort Ts[64 * 256];    // 32 KB
    __shared__ float red[64][4];
    const int t = threadIdx.x;
    const int w = t >> 6, lane = t & 63;
    const int quad = lane >> 4, c15 = lane & 15;
    const ushort* Asrc[4] = {A0, A1, A2, A3};
    const ushort* W1c = Wt1 + (size_t)c * 256 * 512;
    const ushort* W2c = Wt2 + (size_t)c * 256 * 256;

    f32x4 accA[4][4], accB[4][4];
#pragma unroll
    for (int i = 0; i < 4; ++i)
#pragma unroll
        for (int j = 0; j < 4; ++j)
#pragma unroll
            for (int r = 0; r < 4; ++r) { accA[i][j][r] = 0.f; accB[i][j][r] = 0.f; }

    // ---- Phase 1: L1 GEMM, K = 512; W1 chunk staged once per kc, used by
    //      both 64-row halves ----
    for (int kc = 0; kc < 512; kc += 64) {
        const ushort* Ab = Asrc[kc >> 7];
        const int within = kc & 127;
        // stage As (half A) + W1 chunk
#pragma unroll
        for (int i = 0; i < 2; ++i) {
            int lin = (i * 4 + w) * 64 + lane;
            int row = lin >> 3, slot = lin & 7, g = slot ^ (row & 7);
            int grow = rowbaseA + row;
            if (grow >= N) grow = 0;
            const ushort* gp = Ab + (size_t)grow * 128 + within + g * 8;
            __builtin_amdgcn_global_load_lds(
                (const __attribute__((address_space(1))) void*)gp,
                (__attribute__((address_space(3))) void*)&As[(i * 4 + w) * 512],
                16, 0, 0);
        }
#pragma unroll
        for (int i = 0; i < 8; ++i) {
            int lin = (i * 4 + w) * 64 + lane;
            int n = lin >> 3, slot = lin & 7, g = slot ^ (n & 7);
            const ushort* gp = W1c + (size_t)n * 512 + kc + g * 8;
            __builtin_amdgcn_global_load_lds(
                (const __attribute__((address_space(1))) void*)gp,
                (__attribute__((address_space(3))) void*)&Bs[(i * 4 + w) * 512],
                16, 0, 0);
        }
        __syncthreads();
#pragma unroll
        for (int ks = 0; ks < 2; ++ks) {
            const int K8 = ks * 4;
            short8 af[4], bf[4];
#pragma unroll
            for (int tr = 0; tr < 4; ++tr) {
                int r = tr * 16 + c15;
                af[tr] = *(const short8*)&As[r * 64 + (((K8 + quad) ^ (r & 7)) * 8)];
            }
#pragma unroll
            for (int tc = 0; tc < 4; ++tc) {
                int n = w * 64 + tc * 16 + c15;
                bf[tc] = *(const short8*)&Bs[n * 64 + (((K8 + quad) ^ (n & 7)) * 8)];
            }
#pragma unroll
            for (int tr = 0; tr < 4; ++tr)
#pragma unroll
                for (int tc = 0; tc < 4; ++tc)
                    accA[tr][tc] = __builtin_amdgcn_mfma_f32_16x16x32_bf16(
                        af[tr], bf[tc], accA[tr][tc], 0, 0, 0);
        }
        __syncthreads();
        // stage As (half B), reuse staged W1 chunk
#pragma unroll
        for (int i = 0; i < 2; ++i) {
            int lin = (i * 4 + w) * 64 + lane;
            int row = lin >> 3, slot = lin & 7, g = slot ^ (row & 7);
            int grow = rowbaseB + row;
            if (grow >= N) grow = 0;
            const ushort* gp = Ab + (size_t)grow * 128 + within + g * 8;
            __builtin_amdgcn_global_load_lds(
                (const __attribute__((address_space(1))) void*)gp,
                (__attribute__((address_space(3))) void*)&As[(i * 4 + w) * 512],
                16, 0, 0);
        }
        __syncthreads();
#pragma unroll
        for (int ks = 0; ks < 2; ++ks) {
            const int K8 = ks * 4;
            short8 af[4], bf[4];
#pragma unroll
            for (int tr = 0; tr < 4; ++tr) {
                int r = tr * 16 + c15;
                af[tr] = *(const short8*)&As[r * 64 + (((K8 + quad) ^ (r & 7)) * 8)];
            }
#pragma unroll
            for (int tc = 0; tc < 4; ++tc) {
                int n = w * 64 + tc * 16 + c15;
                bf[tc] = *(const short8*)&Bs[n * 64 + (((K8 + quad) ^ (n & 7)) * 8)];
            }
#pragma unroll
            for (int tr = 0; tr < 4; ++tr)
#pragma unroll
                for (int tc = 0; tc < 4; ++tc)
                    accB[tr][tc] = __builtin_amdgcn_mfma_f32_16x16x32_bf16(
                        af[tr], bf[tc], accB[tr][tc], 0, 0, 0);
        }
        __syncthreads();
    }

    // ---- halves: Ts dump -> phase 2 -> phase 3, half A then half B ----
    for (int half = 0; half < 2; ++half) {
        const int rowbase = half ? rowbaseB : rowbaseA;
        f32x4 (*accP)[4] = half ? accB : accA;

        // T1 tile -> Ts (bf16, 32-granule XOR swizzle per row)
#pragma unroll
        for (int tc = 0; tc < 4; ++tc) {
            int col = w * 64 + tc * 16 + c15;
            float bv = b1[c * 256 + col];
#pragma unroll
            for (int tr = 0; tr < 4; ++tr)
#pragma unroll
                for (int rg = 0; rg < 4; ++rg) {
                    int row = tr * 16 + quad * 4 + rg;
                    Ts[row * 256 + (((col >> 3) ^ (row & 31)) * 8) + (col & 7)]
                        = f2bf(fmaxf(accP[tr][tc][rg] + bv, 0.f));
                }
        }
        __syncthreads();

        // Phase 2: L2 GEMM, K = 256 from Ts (accumulate back into accP)
#pragma unroll
        for (int i = 0; i < 4; ++i)
#pragma unroll
            for (int j = 0; j < 4; ++j)
#pragma unroll
                for (int r = 0; r < 4; ++r) accP[i][j][r] = 0.f;

        for (int kc = 0; kc < 256; kc += 64) {
#pragma unroll
            for (int i = 0; i < 8; ++i) {
                int lin = (i * 4 + w) * 64 + lane;
                int n = lin >> 3, slot = lin & 7, g = slot ^ (n & 7);
                const ushort* gp = W2c + (size_t)n * 256 + kc + g * 8;
                __builtin_amdgcn_global_load_lds(
                    (const __attribute__((address_space(1))) void*)gp,
                    (__attribute__((address_space(3))) void*)&Bs[(i * 4 + w) * 512],
                    16, 0, 0);
            }
            __syncthreads();
#pragma unroll
            for (int ks = 0; ks < 2; ++ks) {
                short8 af[4], bf[4];
                const int g0 = (kc >> 3) + ks * 4 + quad;
#pragma unroll
                for (int tr = 0; tr < 4; ++tr) {
                    int r = tr * 16 + c15;
                    af[tr] = *(const short8*)&Ts[r * 256 + ((g0 ^ (r & 31)) * 8)];
                }
#pragma unroll
                for (int tc = 0; tc < 4; ++tc) {
                    int n = w * 64 + tc * 16 + c15;
                    bf[tc] = *(const short8*)&Bs[n * 64 + ((((ks * 4) + quad) ^ (n & 7)) * 8)];
                }
#pragma unroll
                for (int tr = 0; tr < 4; ++tr)
#pragma unroll
                    for (int tc = 0; tc < 4; ++tc)
                        accP[tr][tc] = __builtin_amdgcn_mfma_f32_16x16x32_bf16(
                            af[tr], bf[tc], accP[tr][tc], 0, 0, 0);
            }
            __syncthreads();
        }

        // Phase 3: relu(acc+b2) dot w3
        float b2v[4], w3v[4];
#pragma unroll
        for (int tc = 0; tc < 4; ++tc) {
            int col = w * 64 + tc * 16 + c15;
            b2v[tc] = b2[c * 256 + col];
            w3v[tc] = w3[c * 256 + col];
        }
#pragma unroll
        for (int tr = 0; tr < 4; ++tr)
#pragma unroll
            for (int rg = 0; rg < 4; ++rg) {
                float p = 0.f;
#pragma unroll
                for (int tc = 0; tc < 4; ++tc)
                    p += fmaxf(accP[tr][tc][rg] + b2v[tc], 0.f) * w3v[tc];
                p += __shfl_xor(p, 1);
                p += __shfl_xor(p, 2);
                p += __shfl_xor(p, 4);
                p += __shfl_xor(p, 8);
                if (c15 == 0) red[tr * 16 + quad * 4 + rg][w] = p;
            }
        __syncthreads();
        if (t < 64) {
            int grow = rowbase + t;
            if (grow < N) {
                float s = red[t][0] + red[t][1] + red[t][2] + red[t][3] + b3[c];
                out[(size_t)grow * NCH + c] = fmaxf(s, 0.f);
            }
        }
        __syncthreads();   // red/Ts safe to reuse for half B
    }
}

// ---------------------------------------------------------------------------
// Launch
// ---------------------------------------------------------------------------
extern "C" void kernel_launch(void* const* d_in, const int* in_sizes, int n_in,
                              void* d_out, int out_size, void* d_ws, size_t ws_size,
                              hipStream_t stream) {
    const float* x        = (const float*)d_in[0];
    const int*   eidx     = (const int*)d_in[1];
    const float* convW    = (const float*)d_in[2];
    const float* convB    = (const float*)d_in[3];
    const float* chanW1   = (const float*)d_in[4];
    const float* chanB1   = (const float*)d_in[5];
    const float* chanW2   = (const float*)d_in[6];
    const float* chanB2   = (const float*)d_in[7];
    const float* chanW3   = (const float*)d_in[8];
    const float* chanB3   = (const float*)d_in[9];
    float* out = (float*)d_out;

    const int N = in_sizes[0] / D;      // 100000
    const int E = in_sizes[1] / 2;      // 1600000
    const int* srcp = eidx;
    const int* dstp = eidx + E;
    const int nb = (N + 255) / 256;     // 391

    char* w = (char*)d_ws;
    auto take = [&](size_t bytes) {
        char* p = w;
        w += (bytes + 255) & ~(size_t)255;
        return p;
    };
    ushort* xb     = (ushort*)take((size_t)N * D * 2);
    ushort* h0     = (ushort*)take((size_t)N * D * 2);
    ushort* h1     = (ushort*)take((size_t)N * D * 2);
    ushort* h2     = (ushort*)take((size_t)N * D * 2);
    int*    deg    = (int*)take((size_t)N * 4);
    int*    offs   = (int*)take((size_t)(N + 1) * 4);
    int*    cursor = (int*)take((size_t)N * 4);
    int*    bsum   = (int*)take((size_t)nb * 4);
    int*    boff   = (int*)take((size_t)nb * 4);
    ushort* Wt1b   = (ushort*)take((size_t)NCH * 256 * 512 * 2);
    ushort* Wt2b   = (ushort*)take((size_t)NCH * 256 * 256 * 2);
    ushort* WtC    = (ushort*)take((size_t)NLAYER * 3 * D * D * 2);

    size_t used = (size_t)(w - (char*)d_ws);
    if (used > ws_size) return;
    size_t rem = ws_size - used;
    size_t need_gin = (((size_t)E * 4 + 255) & ~(size_t)255) + (size_t)N * D * 2;
    if (rem < need_gin) return;

    int*    csr = (int*)w;
    ushort* a   = (ushort*)(w + (((size_t)E * 4 + 255) & ~(size_t)255));

    // --- CSR build (XCD-partitioned hist + parallel scan + partitioned fill) ---
    hipMemsetAsync(deg, 0, (size_t)N * 4, stream);
    {
        int nchunks = (E + FILL_CHUNK - 1) / FILL_CHUNK;
        int nPer = (N + 7) / 8;
        hist_part_kernel<<<nchunks * 8, 256, 0, stream>>>(dstp, deg, E, nPer, N);
        blocksum_kernel<<<nb, 256, 0, stream>>>(deg, bsum, N);
        scanblk_kernel<<<1, 512, 0, stream>>>(bsum, boff, nb, offs, N, E);
        blockscan_kernel<<<nb, 256, 0, stream>>>(deg, boff, offs, cursor, N);
        fill_part_kernel<<<nchunks * 8, 256, 0, stream>>>(
            srcp, dstp, cursor, csr, E, nPer, N);
    }

    // --- converts (independent) ---
    cvtx_kernel<<<(N * 16 + 255) / 256, 256, 0, stream>>>(x, xb, N * 16);
    cvtW_kernel<<<dim3(512 / 32, 256 / 32, NCH), 256, 0, stream>>>(chanW1, Wt1b, 512, 256);
    cvtW_kernel<<<dim3(256 / 32, 256 / 32, NCH), 256, 0, stream>>>(chanW2, Wt2b, 256, 256);
    cvtW_kernel<<<dim3(D / 32, D / 32, NLAYER * 3), 256, 0, stream>>>(convW, WtC, D, D);

    const int rowtiles = (N + 127) / 128;
    const int aggblocks = (N * 64 + 255) / 256;

    // --- GIN layers: agg + fused 3-linear MLP per layer ---
    ushort* hbuf[NLAYER] = {h0, h1, h2};
    const ushort* prev = xb;
    for (int l = 0; l < NLAYER; ++l) {
        agg_bf16<<<aggblocks, 256, 0, stream>>>(prev, offs, csr, a, N);
        gin_mlp_mfma<<<rowtiles, 256, 0, stream>>>(
            a, WtC + (size_t)l * 3 * D * D, convB + (size_t)l * 3 * D, hbuf[l], N);
        prev = hbuf[l];
    }

    // --- channel MLPs: fused, 128-row (2x64) tiles, XCD-aware swizzle ---
    {
        const int T = (N + 127) / 128;        // 782 row tiles
        const int chunkT = (T + 7) / 8;       // row tiles per XCD class
        const int grid = 8 * chunkT * NCH;
        chan_fused_mfma<<<grid, 256, 0, stream>>>(
            xb, h0, h1, h2,
            Wt1b, chanB1, Wt2b, chanB2, chanW3, chanB3,
            out, N, T, chunkT);
    }
}

// Round 11
// 1029.805 us; speedup vs baseline: 1.7590x; 1.2819x over previous
//
#include <hip/hip_runtime.h>
#include <hip/hip_bf16.h>

// Problem constants (fixed by the reference)
#define D 128        // feature dim
#define NLAYER 3
#define NCH 4

typedef __attribute__((ext_vector_type(8))) short short8;
typedef __attribute__((ext_vector_type(4))) float f32x4;

__device__ __forceinline__ ushort f2bf(float f) {
    unsigned int u = __builtin_bit_cast(unsigned int, f);
    u += 0x7fffu + ((u >> 16) & 1u);     // RNE
    return (ushort)(u >> 16);
}
__device__ __forceinline__ float bflo(unsigned int u) {
    return __builtin_bit_cast(float, u << 16);
}
__device__ __forceinline__ float bfhi(unsigned int u) {
    return __builtin_bit_cast(float, u & 0xffff0000u);
}

// ---------------------------------------------------------------------------
// CSR construction. hist and fill are XCD-partitioned: class = bid & 7 owns
// one contiguous eighth of dst-space (random 4B atomics stay in one XCD L2).
// ---------------------------------------------------------------------------
#define FILL_CHUNK 4096
__global__ __launch_bounds__(256) void hist_part_kernel(
    const int* __restrict__ dst, int* __restrict__ deg,
    int E, int nPer, int N)
{
    int cls = blockIdx.x & 7;
    int base = (blockIdx.x >> 3) * FILL_CHUNK;
    int lo = cls * nPer;
    int hi = lo + nPer; if (hi > N) hi = N;
    int end = base + FILL_CHUNK; if (end > E) end = E;
    for (int e = base + threadIdx.x; e < end; e += 256) {
        int d = dst[e];
        if (d >= lo && d < hi) atomicAdd(&deg[d], 1);
    }
}

__global__ __launch_bounds__(256) void blocksum_kernel(
    const int* __restrict__ deg, int* __restrict__ bsum, int n)
{
    int i = blockIdx.x * 256 + threadIdx.x;
    int v = (i < n) ? deg[i] : 0;
#pragma unroll
    for (int o = 1; o < 64; o <<= 1) v += __shfl_xor(v, o);
    __shared__ int s[4];
    if ((threadIdx.x & 63) == 0) s[threadIdx.x >> 6] = v;
    __syncthreads();
    if (threadIdx.x == 0) bsum[blockIdx.x] = s[0] + s[1] + s[2] + s[3];
}

__global__ __launch_bounds__(512) void scanblk_kernel(
    const int* __restrict__ bsum, int* __restrict__ boff, int nb,
    int* __restrict__ offs, int n, int E)
{
    __shared__ int sh[512];
    int t = threadIdx.x;
    sh[t] = (t < nb) ? bsum[t] : 0;
    __syncthreads();
    for (int d = 1; d < 512; d <<= 1) {
        int v = (t >= d) ? sh[t - d] : 0;
        __syncthreads();
        sh[t] += v;
        __syncthreads();
    }
    if (t < nb) boff[t] = (t == 0) ? 0 : sh[t - 1];
    if (t == 0) offs[n] = E;
}

__global__ __launch_bounds__(256) void blockscan_kernel(
    const int* __restrict__ deg, const int* __restrict__ boff,
    int* __restrict__ offs, int* __restrict__ cursor, int n)
{
    __shared__ int sh[256];
    int t = threadIdx.x;
    int i = blockIdx.x * 256 + t;
    int v = (i < n) ? deg[i] : 0;
    sh[t] = v;
    __syncthreads();
    for (int d = 1; d < 256; d <<= 1) {
        int u = (t >= d) ? sh[t - d] : 0;
        __syncthreads();
        sh[t] += u;
        __syncthreads();
    }
    if (i < n) {
        int ex = boff[blockIdx.x] + sh[t] - v;
        offs[i] = ex; cursor[i] = ex;
    }
}

__global__ __launch_bounds__(256) void fill_part_kernel(
    const int* __restrict__ src, const int* __restrict__ dst,
    int* __restrict__ cursor, int* __restrict__ csr,
    int E, int nPer, int N)
{
    int cls = blockIdx.x & 7;
    int base = (blockIdx.x >> 3) * FILL_CHUNK;
    int lo = cls * nPer;
    int hi = lo + nPer; if (hi > N) hi = N;
    int end = base + FILL_CHUNK; if (end > E) end = E;
    for (int e = base + threadIdx.x; e < end; e += 256) {
        int d = dst[e];
        int s = src[e];
        if (d >= lo && d < hi) {
            int p = atomicAdd(&cursor[d], 1);
            csr[p] = s;
        }
    }
}

// ---------------------------------------------------------------------------
// fp32 -> bf16 bulk convert (8 elems/thread)
// ---------------------------------------------------------------------------
__global__ __launch_bounds__(256) void cvtx_kernel(
    const float* __restrict__ x, ushort* __restrict__ xb, int total8)
{
    int i = blockIdx.x * 256 + threadIdx.x;
    if (i >= total8) return;
    const float* gp = x + (size_t)i * 8;
    float4 v0 = *(const float4*)gp;
    float4 v1 = *(const float4*)(gp + 4);
    short8 pk;
    pk[0] = (short)f2bf(v0.x); pk[1] = (short)f2bf(v0.y);
    pk[2] = (short)f2bf(v0.z); pk[3] = (short)f2bf(v0.w);
    pk[4] = (short)f2bf(v1.x); pk[5] = (short)f2bf(v1.y);
    pk[6] = (short)f2bf(v1.z); pk[7] = (short)f2bf(v1.w);
    *(short8*)(xb + (size_t)i * 8) = pk;
}

// ---------------------------------------------------------------------------
// Weight transpose + fp32->bf16: Wt[c][n][k] = bf16(W[c][k][n])
// ---------------------------------------------------------------------------
__global__ void cvtW_kernel(const float* __restrict__ W, ushort* __restrict__ Wt,
                            int K, int Ncols) {
    __shared__ float tile[32][33];
    int c = blockIdx.z;
    int k0 = blockIdx.x * 32, n0 = blockIdx.y * 32;
    const float* Wc = W + (size_t)c * K * Ncols;
    ushort* Wtc = Wt + (size_t)c * K * Ncols;
    int tx = threadIdx.x & 31, ty = threadIdx.x >> 5;
#pragma unroll
    for (int i = 0; i < 4; ++i) {
        int k = k0 + ty + i * 8;
        tile[ty + i * 8][tx] = Wc[(size_t)k * Ncols + n0 + tx];
    }
    __syncthreads();
#pragma unroll
    for (int i = 0; i < 4; ++i) {
        int n = n0 + ty + i * 8;
        Wtc[(size_t)n * K + k0 + tx] = f2bf(tile[tx][ty + i * 8]);
    }
}

// ---------------------------------------------------------------------------
// Aggregation (bf16 in/out, fp32 accumulate), one wave per node (100k-wave
// TLP — do NOT fuse into the MLP kernel; R9 proved that collapses TLP 32x).
// ---------------------------------------------------------------------------
__global__ __launch_bounds__(256) void agg_bf16(
    const ushort* __restrict__ h,
    const int* __restrict__ offs, const int* __restrict__ csr,
    ushort* __restrict__ outb, int n)
{
    int wid = (blockIdx.x * 256 + threadIdx.x) >> 6;
    int lane = threadIdx.x & 63;
    if (wid >= n) return;
    const unsigned int* hb = (const unsigned int*)h;
    unsigned int u = hb[(size_t)wid * 64 + lane];
    float ax = bflo(u), ay = bfhi(u);
    int b = offs[wid], e = offs[wid + 1];
    int j = b;
    for (; j + 4 <= e; j += 4) {
        int s0 = csr[j], s1 = csr[j + 1], s2 = csr[j + 2], s3 = csr[j + 3];
        unsigned int u0 = hb[(size_t)s0 * 64 + lane];
        unsigned int u1 = hb[(size_t)s1 * 64 + lane];
        unsigned int u2 = hb[(size_t)s2 * 64 + lane];
        unsigned int u3 = hb[(size_t)s3 * 64 + lane];
        ax += (bflo(u0) + bflo(u1)) + (bflo(u2) + bflo(u3));
        ay += (bfhi(u0) + bfhi(u1)) + (bfhi(u2) + bfhi(u3));
    }
    for (; j < e; ++j) {
        unsigned int u0 = hb[(size_t)csr[j] * 64 + lane];
        ax += bflo(u0); ay += bfhi(u0);
    }
    unsigned int po = (unsigned int)f2bf(ax) | ((unsigned int)f2bf(ay) << 16);
    ((unsigned int*)outb)[(size_t)wid * 64 + lane] = po;
}

// ---------------------------------------------------------------------------
// Fused GIN-layer MLP: Out = relu(relu(relu(A@W0+b0)@W1+b1)@W2+b2)
// ---------------------------------------------------------------------------
__global__ __launch_bounds__(256) void gin_mlp_mfma(
    const ushort* __restrict__ A,
    const ushort* __restrict__ WtL,    // [3][128][128] bf16, n-major
    const float* __restrict__ biasL,   // [3][128]
    ushort* __restrict__ Out,
    int nrows)
{
    __shared__ __align__(16) ushort As[128 * 128];   // 32 KB
    __shared__ __align__(16) ushort Bs[128 * 128];   // 32 KB
    const int t = threadIdx.x;
    const int w = t >> 6, lane = t & 63;
    const int quad = lane >> 4, c15 = lane & 15;
    const int wr = w >> 1, wc = w & 1;
    const int rowbase = blockIdx.x * 128;

#pragma unroll
    for (int i = 0; i < 8; ++i) {
        int lin = (i * 4 + w) * 64 + lane;
        int row = lin >> 4, slot = lin & 15, g = slot ^ (row & 15);
        int grow = rowbase + row;
        if (grow >= nrows) grow = 0;
        const ushort* gp = A + (size_t)grow * 128 + g * 8;
        __builtin_amdgcn_global_load_lds(
            (const __attribute__((address_space(1))) void*)gp,
            (__attribute__((address_space(3))) void*)&As[(i * 4 + w) * 512],
            16, 0, 0);
    }
#pragma unroll
    for (int i = 0; i < 8; ++i) {
        int lin = (i * 4 + w) * 64 + lane;
        int n = lin >> 4, slot = lin & 15, g = slot ^ (n & 15);
        const ushort* gp = WtL + (size_t)n * 128 + g * 8;
        __builtin_amdgcn_global_load_lds(
            (const __attribute__((address_space(1))) void*)gp,
            (__attribute__((address_space(3))) void*)&Bs[(i * 4 + w) * 512],
            16, 0, 0);
    }
    __syncthreads();

    for (int s = 0; s < 3; ++s) {
        f32x4 acc[4][4];
#pragma unroll
        for (int i = 0; i < 4; ++i)
#pragma unroll
            for (int j = 0; j < 4; ++j)
#pragma unroll
                for (int r = 0; r < 4; ++r) acc[i][j][r] = 0.f;

#pragma unroll
        for (int ks = 0; ks < 4; ++ks) {
            short8 af[4], bf[4];
#pragma unroll
            for (int tr = 0; tr < 4; ++tr) {
                int r = wr * 64 + tr * 16 + c15;
                af[tr] = *(const short8*)&As[r * 128 + (((ks * 4 + quad) ^ (r & 15)) * 8)];
            }
#pragma unroll
            for (int tc = 0; tc < 4; ++tc) {
                int n = wc * 64 + tc * 16 + c15;
                bf[tc] = *(const short8*)&Bs[n * 128 + (((ks * 4 + quad) ^ (n & 15)) * 8)];
            }
#pragma unroll
            for (int tr = 0; tr < 4; ++tr)
#pragma unroll
                for (int tc = 0; tc < 4; ++tc)
                    acc[tr][tc] = __builtin_amdgcn_mfma_f32_16x16x32_bf16(
                        af[tr], bf[tc], acc[tr][tc], 0, 0, 0);
        }
        __syncthreads();

        if (s < 2) {
#pragma unroll
            for (int tc = 0; tc < 4; ++tc) {
                int col = wc * 64 + tc * 16 + c15;
                float bv = biasL[s * 128 + col];
#pragma unroll
                for (int tr = 0; tr < 4; ++tr)
#pragma unroll
                    for (int rg = 0; rg < 4; ++rg) {
                        int row = wr * 64 + tr * 16 + quad * 4 + rg;
                        As[row * 128 + (((col >> 3) ^ (row & 15)) * 8) + (col & 7)]
                            = f2bf(fmaxf(acc[tr][tc][rg] + bv, 0.f));
                    }
            }
            const ushort* Wn = WtL + (size_t)(s + 1) * 128 * 128;
#pragma unroll
            for (int i = 0; i < 8; ++i) {
                int lin = (i * 4 + w) * 64 + lane;
                int n = lin >> 4, slot = lin & 15, g = slot ^ (n & 15);
                const ushort* gp = Wn + (size_t)n * 128 + g * 8;
                __builtin_amdgcn_global_load_lds(
                    (const __attribute__((address_space(1))) void*)gp,
                    (__attribute__((address_space(3))) void*)&Bs[(i * 4 + w) * 512],
                    16, 0, 0);
            }
            __syncthreads();
        } else {
#pragma unroll
            for (int tc = 0; tc < 4; ++tc) {
                int col = wc * 64 + tc * 16 + c15;
                float bv = biasL[2 * 128 + col];
#pragma unroll
                for (int tr = 0; tr < 4; ++tr)
#pragma unroll
                    for (int rg = 0; rg < 4; ++rg) {
                        int grow = rowbase + wr * 64 + tr * 16 + quad * 4 + rg;
                        if (grow < nrows)
                            Out[(size_t)grow * 128 + col]
                                = f2bf(fmaxf(acc[tr][tc][rg] + bv, 0.f));
                    }
            }
        }
    }
}

// ---------------------------------------------------------------------------
// Channel-MLP tail (Ts dump -> L2 GEMM -> w3 dot). Takes the accumulator
// array BY REFERENCE and is force-inlined: after inlining all indices are
// static, so acc stays in VGPRs (R10's runtime-selected pointer caused a
// 527 MB scratch spill — never index acc through a runtime pointer).
// ---------------------------------------------------------------------------
__device__ __forceinline__ void chan_tail(
    f32x4 (&acc)[4][4],
    ushort* Bs, ushort* Ts, float (*red)[4],
    const ushort* __restrict__ W2c,
    const float* __restrict__ b2, const float* __restrict__ w3,
    const float* __restrict__ b3,
    float* __restrict__ out,
    int rowbase, int N, int c,
    int w, int lane, int quad, int c15, int t)
{
    // T1 tile -> Ts (bf16, 32-granule XOR swizzle per row)
#pragma unroll
    for (int tc = 0; tc < 4; ++tc) {
        int col = w * 64 + tc * 16 + c15;
        float bv = b2[-256 + 0] * 0.f;   // placeholder no-op (kept out of codegen)
        (void)bv;
    }
    // (b1 bias is applied by caller before this function? No — see below.)
    // NOTE: bias b1 is applied inline in the dump loop by the caller passing
    // pre-biased acc? To keep arithmetic identical we do bias here:
    // -- actual implementation below --
    // This comment block intentionally retained; real code follows.
    __syncthreads();   // ensure previous Ts/red users are done (half B reuse)
    // (the first call's extra barrier is harmless)
    // -- dump with bias+relu happens in caller-provided b1 values --
    // see chan_fused_mfma: it inlines the dump itself before calling tail2.
    (void)Ts; (void)red; (void)W2c; (void)b2; (void)w3; (void)b3; (void)out;
    (void)rowbase; (void)N; (void)c; (void)lane; (void)quad; (void)t; (void)acc; (void)Bs;
}

// ---------------------------------------------------------------------------
// Fully fused channel MLP v4: 128 rows (two 64-row halves) x 1 channel per
// block, 256 threads, 2 blocks/CU. W1 k-chunk staged ONCE per kc, used by
// both halves. Tail duplicated via force-inlined helper with acc by
// reference (spill-safe). XCD-aware swizzle retained. absmax unchanged.
// LDS: As 8K + Bs 32K + Ts 32K + red 1K = 73 KB.
// ---------------------------------------------------------------------------
__device__ __forceinline__ void chan_half_tail(
    f32x4 (&acc)[4][4],
    ushort* __restrict__ Bs, ushort* __restrict__ Ts, float (*red)[4],
    const ushort* __restrict__ W2c,
    const float* __restrict__ b1, const float* __restrict__ b2,
    const float* __restrict__ w3, const float* __restrict__ b3,
    float* __restrict__ out,
    int rowbase, int N, int c,
    int w, int lane, int quad, int c15, int t)
{
    // ---- Ts dump: relu(acc + b1) -> bf16, 32-granule XOR swizzle ----
#pragma unroll
    for (int tc = 0; tc < 4; ++tc) {
        int col = w * 64 + tc * 16 + c15;
        float bv = b1[c * 256 + col];
#pragma unroll
        for (int tr = 0; tr < 4; ++tr)
#pragma unroll
            for (int rg = 0; rg < 4; ++rg) {
                int row = tr * 16 + quad * 4 + rg;
                Ts[row * 256 + (((col >> 3) ^ (row & 31)) * 8) + (col & 7)]
                    = f2bf(fmaxf(acc[tr][tc][rg] + bv, 0.f));
            }
    }
    __syncthreads();

    // ---- Phase 2: L2 GEMM, K = 256 from Ts ----
#pragma unroll
    for (int i = 0; i < 4; ++i)
#pragma unroll
        for (int j = 0; j < 4; ++j)
#pragma unroll
            for (int r = 0; r < 4; ++r) acc[i][j][r] = 0.f;

    for (int kc = 0; kc < 256; kc += 64) {
#pragma unroll
        for (int i = 0; i < 8; ++i) {
            int lin = (i * 4 + w) * 64 + lane;
            int n = lin >> 3, slot = lin & 7, g = slot ^ (n & 7);
            const ushort* gp = W2c + (size_t)n * 256 + kc + g * 8;
            __builtin_amdgcn_global_load_lds(
                (const __attribute__((address_space(1))) void*)gp,
                (__attribute__((address_space(3))) void*)&Bs[(i * 4 + w) * 512],
                16, 0, 0);
        }
        __syncthreads();
#pragma unroll
        for (int ks = 0; ks < 2; ++ks) {
            short8 af[4], bf[4];
            const int g0 = (kc >> 3) + ks * 4 + quad;
#pragma unroll
            for (int tr = 0; tr < 4; ++tr) {
                int r = tr * 16 + c15;
                af[tr] = *(const short8*)&Ts[r * 256 + ((g0 ^ (r & 31)) * 8)];
            }
#pragma unroll
            for (int tc = 0; tc < 4; ++tc) {
                int n = w * 64 + tc * 16 + c15;
                bf[tc] = *(const short8*)&Bs[n * 64 + ((((ks * 4) + quad) ^ (n & 7)) * 8)];
            }
#pragma unroll
            for (int tr = 0; tr < 4; ++tr)
#pragma unroll
                for (int tc = 0; tc < 4; ++tc)
                    acc[tr][tc] = __builtin_amdgcn_mfma_f32_16x16x32_bf16(
                        af[tr], bf[tc], acc[tr][tc], 0, 0, 0);
        }
        __syncthreads();
    }

    // ---- Phase 3: relu(acc+b2) dot w3 ----
    float b2v[4], w3v[4];
#pragma unroll
    for (int tc = 0; tc < 4; ++tc) {
        int col = w * 64 + tc * 16 + c15;
        b2v[tc] = b2[c * 256 + col];
        w3v[tc] = w3[c * 256 + col];
    }
#pragma unroll
    for (int tr = 0; tr < 4; ++tr)
#pragma unroll
        for (int rg = 0; rg < 4; ++rg) {
            float p = 0.f;
#pragma unroll
            for (int tc = 0; tc < 4; ++tc)
                p += fmaxf(acc[tr][tc][rg] + b2v[tc], 0.f) * w3v[tc];
            p += __shfl_xor(p, 1);
            p += __shfl_xor(p, 2);
            p += __shfl_xor(p, 4);
            p += __shfl_xor(p, 8);
            if (c15 == 0) red[tr * 16 + quad * 4 + rg][w] = p;
        }
    __syncthreads();
    if (t < 64) {
        int grow = rowbase + t;
        if (grow < N) {
            float s = red[t][0] + red[t][1] + red[t][2] + red[t][3] + b3[c];
            out[(size_t)grow * NCH + c] = fmaxf(s, 0.f);
        }
    }
    __syncthreads();   // Ts/red safe for next half
}

__global__ __launch_bounds__(256, 2) void chan_fused_mfma(
    const ushort* __restrict__ A0, const ushort* __restrict__ A1,
    const ushort* __restrict__ A2, const ushort* __restrict__ A3,
    const ushort* __restrict__ Wt1,    // [NCH*256][512] bf16 n-major
    const float* __restrict__ b1,      // [NCH*256]
    const ushort* __restrict__ Wt2,    // [NCH][256][256] bf16 n-major
    const float* __restrict__ b2,      // [NCH*256]
    const float* __restrict__ w3,      // [NCH*256]
    const float* __restrict__ b3,      // [NCH]
    float* __restrict__ out,           // [N, NCH]
    int N, int T, int chunkT)
{
    const int bid = blockIdx.x;
    const int xcd = bid & 7;
    const int idx = bid >> 3;
    const int c = idx & 3;
    const int rt = xcd * chunkT + (idx >> 2);
    if (rt >= T) return;
    const int rowbaseA = rt * 128;
    const int rowbaseB = rowbaseA + 64;

    __shared__ __align__(16) ushort As[64 * 64];     //  8 KB
    __shared__ __align__(16) ushort Bs[256 * 64];    // 32 KB
    __shared__ __align__(16) ushort Ts[64 * 256];    // 32 KB
    __shared__ float red[64][4];
    const int t = threadIdx.x;
    const int w = t >> 6, lane = t & 63;
    const int quad = lane >> 4, c15 = lane & 15;
    const ushort* Asrc[4] = {A0, A1, A2, A3};
    const ushort* W1c = Wt1 + (size_t)c * 256 * 512;
    const ushort* W2c = Wt2 + (size_t)c * 256 * 256;

    f32x4 accA[4][4], accB[4][4];
#pragma unroll
    for (int i = 0; i < 4; ++i)
#pragma unroll
        for (int j = 0; j < 4; ++j)
#pragma unroll
            for (int r = 0; r < 4; ++r) { accA[i][j][r] = 0.f; accB[i][j][r] = 0.f; }

    // ---- Phase 1: L1 GEMM, K = 512; W1 chunk staged once per kc ----
    for (int kc = 0; kc < 512; kc += 64) {
        const ushort* Ab = Asrc[kc >> 7];
        const int within = kc & 127;
#pragma unroll
        for (int i = 0; i < 2; ++i) {
            int lin = (i * 4 + w) * 64 + lane;
            int row = lin >> 3, slot = lin & 7, g = slot ^ (row & 7);
            int grow = rowbaseA + row;
            if (grow >= N) grow = 0;
            const ushort* gp = Ab + (size_t)grow * 128 + within + g * 8;
            __builtin_amdgcn_global_load_lds(
                (const __attribute__((address_space(1))) void*)gp,
                (__attribute__((address_space(3))) void*)&As[(i * 4 + w) * 512],
                16, 0, 0);
        }
#pragma unroll
        for (int i = 0; i < 8; ++i) {
            int lin = (i * 4 + w) * 64 + lane;
            int n = lin >> 3, slot = lin & 7, g = slot ^ (n & 7);
            const ushort* gp = W1c + (size_t)n * 512 + kc + g * 8;
            __builtin_amdgcn_global_load_lds(
                (const __attribute__((address_space(1))) void*)gp,
                (__attribute__((address_space(3))) void*)&Bs[(i * 4 + w) * 512],
                16, 0, 0);
        }
        __syncthreads();
#pragma unroll
        for (int ks = 0; ks < 2; ++ks) {
            const int K8 = ks * 4;
            short8 af[4], bf[4];
#pragma unroll
            for (int tr = 0; tr < 4; ++tr) {
                int r = tr * 16 + c15;
                af[tr] = *(const short8*)&As[r * 64 + (((K8 + quad) ^ (r & 7)) * 8)];
            }
#pragma unroll
            for (int tc = 0; tc < 4; ++tc) {
                int n = w * 64 + tc * 16 + c15;
                bf[tc] = *(const short8*)&Bs[n * 64 + (((K8 + quad) ^ (n & 7)) * 8)];
            }
#pragma unroll
            for (int tr = 0; tr < 4; ++tr)
#pragma unroll
                for (int tc = 0; tc < 4; ++tc)
                    accA[tr][tc] = __builtin_amdgcn_mfma_f32_16x16x32_bf16(
                        af[tr], bf[tc], accA[tr][tc], 0, 0, 0);
        }
        __syncthreads();
        // restage As with half B rows; W1 chunk in Bs is reused
#pragma unroll
        for (int i = 0; i < 2; ++i) {
            int lin = (i * 4 + w) * 64 + lane;
            int row = lin >> 3, slot = lin & 7, g = slot ^ (row & 7);
            int grow = rowbaseB + row;
            if (grow >= N) grow = 0;
            const ushort* gp = Ab + (size_t)grow * 128 + within + g * 8;
            __builtin_amdgcn_global_load_lds(
                (const __attribute__((address_space(1))) void*)gp,
                (__attribute__((address_space(3))) void*)&As[(i * 4 + w) * 512],
                16, 0, 0);
        }
        __syncthreads();
#pragma unroll
        for (int ks = 0; ks < 2; ++ks) {
            const int K8 = ks * 4;
            short8 af[4], bf[4];
#pragma unroll
            for (int tr = 0; tr < 4; ++tr) {
                int r = tr * 16 + c15;
                af[tr] = *(const short8*)&As[r * 64 + (((K8 + quad) ^ (r & 7)) * 8)];
            }
#pragma unroll
            for (int tc = 0; tc < 4; ++tc) {
                int n = w * 64 + tc * 16 + c15;
                bf[tc] = *(const short8*)&Bs[n * 64 + (((K8 + quad) ^ (n & 7)) * 8)];
            }
#pragma unroll
            for (int tr = 0; tr < 4; ++tr)
#pragma unroll
                for (int tc = 0; tc < 4; ++tc)
                    accB[tr][tc] = __builtin_amdgcn_mfma_f32_16x16x32_bf16(
                        af[tr], bf[tc], accB[tr][tc], 0, 0, 0);
        }
        __syncthreads();
    }

    // ---- tails: half A then half B (static acc references, no spill) ----
    chan_half_tail(accA, Bs, Ts, red, W2c, b1, b2, w3, b3, out,
                   rowbaseA, N, c, w, lane, quad, c15, t);
    chan_half_tail(accB, Bs, Ts, red, W2c, b1, b2, w3, b3, out,
                   rowbaseB, N, c, w, lane, quad, c15, t);
}

// ---------------------------------------------------------------------------
// Launch
// ---------------------------------------------------------------------------
extern "C" void kernel_launch(void* const* d_in, const int* in_sizes, int n_in,
                              void* d_out, int out_size, void* d_ws, size_t ws_size,
                              hipStream_t stream) {
    const float* x        = (const float*)d_in[0];
    const int*   eidx     = (const int*)d_in[1];
    const float* convW    = (const float*)d_in[2];
    const float* convB    = (const float*)d_in[3];
    const float* chanW1   = (const float*)d_in[4];
    const float* chanB1   = (const float*)d_in[5];
    const float* chanW2   = (const float*)d_in[6];
    const float* chanB2   = (const float*)d_in[7];
    const float* chanW3   = (const float*)d_in[8];
    const float* chanB3   = (const float*)d_in[9];
    float* out = (float*)d_out;

    const int N = in_sizes[0] / D;      // 100000
    const int E = in_sizes[1] / 2;      // 1600000
    const int* srcp = eidx;
    const int* dstp = eidx + E;
    const int nb = (N + 255) / 256;     // 391

    char* w = (char*)d_ws;
    auto take = [&](size_t bytes) {
        char* p = w;
        w += (bytes + 255) & ~(size_t)255;
        return p;
    };
    ushort* xb     = (ushort*)take((size_t)N * D * 2);
    ushort* h0     = (ushort*)take((size_t)N * D * 2);
    ushort* h1     = (ushort*)take((size_t)N * D * 2);
    ushort* h2     = (ushort*)take((size_t)N * D * 2);
    int*    deg    = (int*)take((size_t)N * 4);
    int*    offs   = (int*)take((size_t)(N + 1) * 4);
    int*    cursor = (int*)take((size_t)N * 4);
    int*    bsum   = (int*)take((size_t)nb * 4);
    int*    boff   = (int*)take((size_t)nb * 4);
    ushort* Wt1b   = (ushort*)take((size_t)NCH * 256 * 512 * 2);
    ushort* Wt2b   = (ushort*)take((size_t)NCH * 256 * 256 * 2);
    ushort* WtC    = (ushort*)take((size_t)NLAYER * 3 * D * D * 2);

    size_t used = (size_t)(w - (char*)d_ws);
    if (used > ws_size) return;
    size_t rem = ws_size - used;
    size_t need_gin = (((size_t)E * 4 + 255) & ~(size_t)255) + (size_t)N * D * 2;
    if (rem < need_gin) return;

    int*    csr = (int*)w;
    ushort* a   = (ushort*)(w + (((size_t)E * 4 + 255) & ~(size_t)255));

    // --- CSR build (XCD-partitioned hist + parallel scan + partitioned fill) ---
    hipMemsetAsync(deg, 0, (size_t)N * 4, stream);
    {
        int nchunks = (E + FILL_CHUNK - 1) / FILL_CHUNK;
        int nPer = (N + 7) / 8;
        hist_part_kernel<<<nchunks * 8, 256, 0, stream>>>(dstp, deg, E, nPer, N);
        blocksum_kernel<<<nb, 256, 0, stream>>>(deg, bsum, N);
        scanblk_kernel<<<1, 512, 0, stream>>>(bsum, boff, nb, offs, N, E);
        blockscan_kernel<<<nb, 256, 0, stream>>>(deg, boff, offs, cursor, N);
        fill_part_kernel<<<nchunks * 8, 256, 0, stream>>>(
            srcp, dstp, cursor, csr, E, nPer, N);
    }

    // --- converts (independent) ---
    cvtx_kernel<<<(N * 16 + 255) / 256, 256, 0, stream>>>(x, xb, N * 16);
    cvtW_kernel<<<dim3(512 / 32, 256 / 32, NCH), 256, 0, stream>>>(chanW1, Wt1b, 512, 256);
    cvtW_kernel<<<dim3(256 / 32, 256 / 32, NCH), 256, 0, stream>>>(chanW2, Wt2b, 256, 256);
    cvtW_kernel<<<dim3(D / 32, D / 32, NLAYER * 3), 256, 0, stream>>>(convW, WtC, D, D);

    const int rowtiles = (N + 127) / 128;
    const int aggblocks = (N * 64 + 255) / 256;

    // --- GIN layers: agg + fused 3-linear MLP per layer ---
    ushort* hbuf[NLAYER] = {h0, h1, h2};
    const ushort* prev = xb;
    for (int l = 0; l < NLAYER; ++l) {
        agg_bf16<<<aggblocks, 256, 0, stream>>>(prev, offs, csr, a, N);
        gin_mlp_mfma<<<rowtiles, 256, 0, stream>>>(
            a, WtC + (size_t)l * 3 * D * D, convB + (size_t)l * 3 * D, hbuf[l], N);
        prev = hbuf[l];
    }

    // --- channel MLPs: fused, 128-row (2x64) tiles, XCD-aware swizzle ---
    {
        const int T = (N + 127) / 128;        // 782 row tiles
        const int chunkT = (T + 7) / 8;       // row tiles per XCD class
        const int grid = 8 * chunkT * NCH;
        chan_fused_mfma<<<grid, 256, 0, stream>>>(
            xb, h0, h1, h2,
            Wt1b, chanB1, Wt2b, chanB2, chanW3, chanB3,
            out, N, T, chunkT);
    }
}

// Round 12
// 834.301 us; speedup vs baseline: 2.1712x; 1.2343x over previous
//
#include <hip/hip_runtime.h>
#include <hip/hip_bf16.h>

// Problem constants (fixed by the reference)
#define D 128        // feature dim
#define NLAYER 3
#define NCH 4

typedef __attribute__((ext_vector_type(8))) short short8;
typedef __attribute__((ext_vector_type(4))) float f32x4;

__device__ __forceinline__ ushort f2bf(float f) {
    unsigned int u = __builtin_bit_cast(unsigned int, f);
    u += 0x7fffu + ((u >> 16) & 1u);     // RNE
    return (ushort)(u >> 16);
}
__device__ __forceinline__ float bflo(unsigned int u) {
    return __builtin_bit_cast(float, u << 16);
}
__device__ __forceinline__ float bfhi(unsigned int u) {
    return __builtin_bit_cast(float, u & 0xffff0000u);
}

// ---------------------------------------------------------------------------
// CSR construction. hist and fill are XCD-partitioned: class = bid & 7 owns
// one contiguous eighth of dst-space (random 4B atomics stay in one XCD L2).
// ---------------------------------------------------------------------------
#define FILL_CHUNK 4096
__global__ __launch_bounds__(256) void hist_part_kernel(
    const int* __restrict__ dst, int* __restrict__ deg,
    int E, int nPer, int N)
{
    int cls = blockIdx.x & 7;
    int base = (blockIdx.x >> 3) * FILL_CHUNK;
    int lo = cls * nPer;
    int hi = lo + nPer; if (hi > N) hi = N;
    int end = base + FILL_CHUNK; if (end > E) end = E;
    for (int e = base + threadIdx.x; e < end; e += 256) {
        int d = dst[e];
        if (d >= lo && d < hi) atomicAdd(&deg[d], 1);
    }
}

__global__ __launch_bounds__(256) void blocksum_kernel(
    const int* __restrict__ deg, int* __restrict__ bsum, int n)
{
    int i = blockIdx.x * 256 + threadIdx.x;
    int v = (i < n) ? deg[i] : 0;
#pragma unroll
    for (int o = 1; o < 64; o <<= 1) v += __shfl_xor(v, o);
    __shared__ int s[4];
    if ((threadIdx.x & 63) == 0) s[threadIdx.x >> 6] = v;
    __syncthreads();
    if (threadIdx.x == 0) bsum[blockIdx.x] = s[0] + s[1] + s[2] + s[3];
}

__global__ __launch_bounds__(512) void scanblk_kernel(
    const int* __restrict__ bsum, int* __restrict__ boff, int nb,
    int* __restrict__ offs, int n, int E)
{
    __shared__ int sh[512];
    int t = threadIdx.x;
    sh[t] = (t < nb) ? bsum[t] : 0;
    __syncthreads();
    for (int d = 1; d < 512; d <<= 1) {
        int v = (t >= d) ? sh[t - d] : 0;
        __syncthreads();
        sh[t] += v;
        __syncthreads();
    }
    if (t < nb) boff[t] = (t == 0) ? 0 : sh[t - 1];
    if (t == 0) offs[n] = E;
}

__global__ __launch_bounds__(256) void blockscan_kernel(
    const int* __restrict__ deg, const int* __restrict__ boff,
    int* __restrict__ offs, int* __restrict__ cursor, int n)
{
    __shared__ int sh[256];
    int t = threadIdx.x;
    int i = blockIdx.x * 256 + t;
    int v = (i < n) ? deg[i] : 0;
    sh[t] = v;
    __syncthreads();
    for (int d = 1; d < 256; d <<= 1) {
        int u = (t >= d) ? sh[t - d] : 0;
        __syncthreads();
        sh[t] += u;
        __syncthreads();
    }
    if (i < n) {
        int ex = boff[blockIdx.x] + sh[t] - v;
        offs[i] = ex; cursor[i] = ex;
    }
}

__global__ __launch_bounds__(256) void fill_part_kernel(
    const int* __restrict__ src, const int* __restrict__ dst,
    int* __restrict__ cursor, int* __restrict__ csr,
    int E, int nPer, int N)
{
    int cls = blockIdx.x & 7;
    int base = (blockIdx.x >> 3) * FILL_CHUNK;
    int lo = cls * nPer;
    int hi = lo + nPer; if (hi > N) hi = N;
    int end = base + FILL_CHUNK; if (end > E) end = E;
    for (int e = base + threadIdx.x; e < end; e += 256) {
        int d = dst[e];
        int s = src[e];
        if (d >= lo && d < hi) {
            int p = atomicAdd(&cursor[d], 1);
            csr[p] = s;
        }
    }
}

// ---------------------------------------------------------------------------
// fp32 -> bf16 bulk convert (8 elems/thread)
// ---------------------------------------------------------------------------
__global__ __launch_bounds__(256) void cvtx_kernel(
    const float* __restrict__ x, ushort* __restrict__ xb, int total8)
{
    int i = blockIdx.x * 256 + threadIdx.x;
    if (i >= total8) return;
    const float* gp = x + (size_t)i * 8;
    float4 v0 = *(const float4*)gp;
    float4 v1 = *(const float4*)(gp + 4);
    short8 pk;
    pk[0] = (short)f2bf(v0.x); pk[1] = (short)f2bf(v0.y);
    pk[2] = (short)f2bf(v0.z); pk[3] = (short)f2bf(v0.w);
    pk[4] = (short)f2bf(v1.x); pk[5] = (short)f2bf(v1.y);
    pk[6] = (short)f2bf(v1.z); pk[7] = (short)f2bf(v1.w);
    *(short8*)(xb + (size_t)i * 8) = pk;
}

// ---------------------------------------------------------------------------
// Weight transpose + fp32->bf16: Wt[c][n][k] = bf16(W[c][k][n])
// ---------------------------------------------------------------------------
__global__ void cvtW_kernel(const float* __restrict__ W, ushort* __restrict__ Wt,
                            int K, int Ncols) {
    __shared__ float tile[32][33];
    int c = blockIdx.z;
    int k0 = blockIdx.x * 32, n0 = blockIdx.y * 32;
    const float* Wc = W + (size_t)c * K * Ncols;
    ushort* Wtc = Wt + (size_t)c * K * Ncols;
    int tx = threadIdx.x & 31, ty = threadIdx.x >> 5;
#pragma unroll
    for (int i = 0; i < 4; ++i) {
        int k = k0 + ty + i * 8;
        tile[ty + i * 8][tx] = Wc[(size_t)k * Ncols + n0 + tx];
    }
    __syncthreads();
#pragma unroll
    for (int i = 0; i < 4; ++i) {
        int n = n0 + ty + i * 8;
        Wtc[(size_t)n * K + k0 + tx] = f2bf(tile[tx][ty + i * 8]);
    }
}

// ---------------------------------------------------------------------------
// Aggregation v2 (bf16 in/out, fp32 accumulate): 4 nodes per wave — each
// 16-lane quarter-wave owns one node, lane reads 16 B (8 bf16 cols) of the
// 256 B row. 4x memory-level parallelism vs one-node-per-wave (16 lines in
// flight per gather instruction). Per-column accumulation keeps the exact
// (a+b)+(c+d) unroll-4 grouping + f2bf rounding -> bit-identical to v1.
// Do NOT fuse into the MLP kernel (R9: 32x TLP collapse, 2x regression).
// ---------------------------------------------------------------------------
__global__ __launch_bounds__(256) void agg_bf16(
    const ushort* __restrict__ h,
    const int* __restrict__ offs, const int* __restrict__ csr,
    ushort* __restrict__ outb, int n)
{
    int node = (blockIdx.x * 256 + threadIdx.x) >> 4;   // quarter-wave id
    int l16 = threadIdx.x & 15;
    if (node >= n) return;
    const uint4* hb = (const uint4*)h;                  // row = 16 uint4
    uint4 u = hb[(size_t)node * 16 + l16 >> 0];
    u = *((const uint4*)(h + (size_t)node * 128) + l16);
    float a0 = bflo(u.x), a1 = bfhi(u.x);
    float a2 = bflo(u.y), a3 = bfhi(u.y);
    float a4 = bflo(u.z), a5 = bfhi(u.z);
    float a6 = bflo(u.w), a7 = bfhi(u.w);
    int b = offs[node], e = offs[node + 1];
    int j = b;
    for (; j + 4 <= e; j += 4) {
        int s0 = csr[j], s1 = csr[j + 1], s2 = csr[j + 2], s3 = csr[j + 3];
        uint4 v0 = *((const uint4*)(h + (size_t)s0 * 128) + l16);
        uint4 v1 = *((const uint4*)(h + (size_t)s1 * 128) + l16);
        uint4 v2 = *((const uint4*)(h + (size_t)s2 * 128) + l16);
        uint4 v3 = *((const uint4*)(h + (size_t)s3 * 128) + l16);
        a0 += (bflo(v0.x) + bflo(v1.x)) + (bflo(v2.x) + bflo(v3.x));
        a1 += (bfhi(v0.x) + bfhi(v1.x)) + (bfhi(v2.x) + bfhi(v3.x));
        a2 += (bflo(v0.y) + bflo(v1.y)) + (bflo(v2.y) + bflo(v3.y));
        a3 += (bfhi(v0.y) + bfhi(v1.y)) + (bfhi(v2.y) + bfhi(v3.y));
        a4 += (bflo(v0.z) + bflo(v1.z)) + (bflo(v2.z) + bflo(v3.z));
        a5 += (bfhi(v0.z) + bfhi(v1.z)) + (bfhi(v2.z) + bfhi(v3.z));
        a6 += (bflo(v0.w) + bflo(v1.w)) + (bflo(v2.w) + bflo(v3.w));
        a7 += (bfhi(v0.w) + bfhi(v1.w)) + (bfhi(v2.w) + bfhi(v3.w));
    }
    for (; j < e; ++j) {
        uint4 v0 = *((const uint4*)(h + (size_t)csr[j] * 128) + l16);
        a0 += bflo(v0.x); a1 += bfhi(v0.x);
        a2 += bflo(v0.y); a3 += bfhi(v0.y);
        a4 += bflo(v0.z); a5 += bfhi(v0.z);
        a6 += bflo(v0.w); a7 += bfhi(v0.w);
    }
    uint4 po;
    po.x = (unsigned int)f2bf(a0) | ((unsigned int)f2bf(a1) << 16);
    po.y = (unsigned int)f2bf(a2) | ((unsigned int)f2bf(a3) << 16);
    po.z = (unsigned int)f2bf(a4) | ((unsigned int)f2bf(a5) << 16);
    po.w = (unsigned int)f2bf(a6) | ((unsigned int)f2bf(a7) << 16);
    *((uint4*)(outb + (size_t)node * 128) + l16) = po;
}

// ---------------------------------------------------------------------------
// Fused GIN-layer MLP: Out = relu(relu(relu(A@W0+b0)@W1+b1)@W2+b2)
// ---------------------------------------------------------------------------
__global__ __launch_bounds__(256) void gin_mlp_mfma(
    const ushort* __restrict__ A,
    const ushort* __restrict__ WtL,    // [3][128][128] bf16, n-major
    const float* __restrict__ biasL,   // [3][128]
    ushort* __restrict__ Out,
    int nrows)
{
    __shared__ __align__(16) ushort As[128 * 128];   // 32 KB
    __shared__ __align__(16) ushort Bs[128 * 128];   // 32 KB
    const int t = threadIdx.x;
    const int w = t >> 6, lane = t & 63;
    const int quad = lane >> 4, c15 = lane & 15;
    const int wr = w >> 1, wc = w & 1;
    const int rowbase = blockIdx.x * 128;

#pragma unroll
    for (int i = 0; i < 8; ++i) {
        int lin = (i * 4 + w) * 64 + lane;
        int row = lin >> 4, slot = lin & 15, g = slot ^ (row & 15);
        int grow = rowbase + row;
        if (grow >= nrows) grow = 0;
        const ushort* gp = A + (size_t)grow * 128 + g * 8;
        __builtin_amdgcn_global_load_lds(
            (const __attribute__((address_space(1))) void*)gp,
            (__attribute__((address_space(3))) void*)&As[(i * 4 + w) * 512],
            16, 0, 0);
    }
#pragma unroll
    for (int i = 0; i < 8; ++i) {
        int lin = (i * 4 + w) * 64 + lane;
        int n = lin >> 4, slot = lin & 15, g = slot ^ (n & 15);
        const ushort* gp = WtL + (size_t)n * 128 + g * 8;
        __builtin_amdgcn_global_load_lds(
            (const __attribute__((address_space(1))) void*)gp,
            (__attribute__((address_space(3))) void*)&Bs[(i * 4 + w) * 512],
            16, 0, 0);
    }
    __syncthreads();

    for (int s = 0; s < 3; ++s) {
        f32x4 acc[4][4];
#pragma unroll
        for (int i = 0; i < 4; ++i)
#pragma unroll
            for (int j = 0; j < 4; ++j)
#pragma unroll
                for (int r = 0; r < 4; ++r) acc[i][j][r] = 0.f;

#pragma unroll
        for (int ks = 0; ks < 4; ++ks) {
            short8 af[4], bf[4];
#pragma unroll
            for (int tr = 0; tr < 4; ++tr) {
                int r = wr * 64 + tr * 16 + c15;
                af[tr] = *(const short8*)&As[r * 128 + (((ks * 4 + quad) ^ (r & 15)) * 8)];
            }
#pragma unroll
            for (int tc = 0; tc < 4; ++tc) {
                int n = wc * 64 + tc * 16 + c15;
                bf[tc] = *(const short8*)&Bs[n * 128 + (((ks * 4 + quad) ^ (n & 15)) * 8)];
            }
#pragma unroll
            for (int tr = 0; tr < 4; ++tr)
#pragma unroll
                for (int tc = 0; tc < 4; ++tc)
                    acc[tr][tc] = __builtin_amdgcn_mfma_f32_16x16x32_bf16(
                        af[tr], bf[tc], acc[tr][tc], 0, 0, 0);
        }
        __syncthreads();

        if (s < 2) {
#pragma unroll
            for (int tc = 0; tc < 4; ++tc) {
                int col = wc * 64 + tc * 16 + c15;
                float bv = biasL[s * 128 + col];
#pragma unroll
                for (int tr = 0; tr < 4; ++tr)
#pragma unroll
                    for (int rg = 0; rg < 4; ++rg) {
                        int row = wr * 64 + tr * 16 + quad * 4 + rg;
                        As[row * 128 + (((col >> 3) ^ (row & 15)) * 8) + (col & 7)]
                            = f2bf(fmaxf(acc[tr][tc][rg] + bv, 0.f));
                    }
            }
            const ushort* Wn = WtL + (size_t)(s + 1) * 128 * 128;
#pragma unroll
            for (int i = 0; i < 8; ++i) {
                int lin = (i * 4 + w) * 64 + lane;
                int n = lin >> 4, slot = lin & 15, g = slot ^ (n & 15);
                const ushort* gp = Wn + (size_t)n * 128 + g * 8;
                __builtin_amdgcn_global_load_lds(
                    (const __attribute__((address_space(1))) void*)gp,
                    (__attribute__((address_space(3))) void*)&Bs[(i * 4 + w) * 512],
                    16, 0, 0);
            }
            __syncthreads();
        } else {
#pragma unroll
            for (int tc = 0; tc < 4; ++tc) {
                int col = wc * 64 + tc * 16 + c15;
                float bv = biasL[2 * 128 + col];
#pragma unroll
                for (int tr = 0; tr < 4; ++tr)
#pragma unroll
                    for (int rg = 0; rg < 4; ++rg) {
                        int grow = rowbase + wr * 64 + tr * 16 + quad * 4 + rg;
                        if (grow < nrows)
                            Out[(size_t)grow * 128 + col]
                                = f2bf(fmaxf(acc[tr][tc][rg] + bv, 0.f));
                    }
            }
        }
    }
}

// ---------------------------------------------------------------------------
// Fully fused channel MLP (exact R8 version — known 240 us, no spill):
// 64 rows x 1 channel per block, 256 threads, 2 blocks/CU, XCD-aware swizzle
// (xcd = bid & 7 owns a contiguous chunk of row tiles -> A-tile L2 reuse,
// FETCH 215->56 MB measured). ONE 4x4 f32x4 accumulator per thread — R10/R11
// proved a second live accumulator array forces a scratch spill.
// LDS: As 8K + Bs 32K + Ts 32K + red 1K = 73 KB.
// ---------------------------------------------------------------------------
__global__ __launch_bounds__(256, 2) void chan_fused_mfma(
    const ushort* __restrict__ A0, const ushort* __restrict__ A1,
    const ushort* __restrict__ A2, const ushort* __restrict__ A3,
    const ushort* __restrict__ Wt1,    // [NCH*256][512] bf16 n-major
    const float* __restrict__ b1,      // [NCH*256]
    const ushort* __restrict__ Wt2,    // [NCH][256][256] bf16 n-major
    const float* __restrict__ b2,      // [NCH*256]
    const float* __restrict__ w3,      // [NCH*256]
    const float* __restrict__ b3,      // [NCH]
    float* __restrict__ out,           // [N, NCH]
    int N, int T, int chunkT)
{
    const int bid = blockIdx.x;
    const int xcd = bid & 7;
    const int idx = bid >> 3;
    const int c = idx & 3;
    const int rt = xcd * chunkT + (idx >> 2);
    if (rt >= T) return;
    const int rowbase = rt * 64;

    __shared__ __align__(16) ushort As[64 * 64];     //  8 KB
    __shared__ __align__(16) ushort Bs[256 * 64];    // 32 KB
    __shared__ __align__(16) ushort Ts[64 * 256];    // 32 KB
    __shared__ float red[64][4];
    const int t = threadIdx.x;
    const int w = t >> 6, lane = t & 63;
    const int quad = lane >> 4, c15 = lane & 15;
    const ushort* Asrc[4] = {A0, A1, A2, A3};
    const ushort* W1c = Wt1 + (size_t)c * 256 * 512;
    const ushort* W2c = Wt2 + (size_t)c * 256 * 256;

    f32x4 acc[4][4];
#pragma unroll
    for (int i = 0; i < 4; ++i)
#pragma unroll
        for (int j = 0; j < 4; ++j)
#pragma unroll
            for (int r = 0; r < 4; ++r) acc[i][j][r] = 0.f;

    // ---- Phase 1: L1 GEMM, K = 512 over the 4 virtual-concat slices ----
    for (int kc = 0; kc < 512; kc += 64) {
        const ushort* Ab = Asrc[kc >> 7];
        const int within = kc & 127;
#pragma unroll
        for (int i = 0; i < 2; ++i) {
            int lin = (i * 4 + w) * 64 + lane;
            int row = lin >> 3, slot = lin & 7, g = slot ^ (row & 7);
            int grow = rowbase + row;
            if (grow >= N) grow = 0;
            const ushort* gp = Ab + (size_t)grow * 128 + within + g * 8;
            __builtin_amdgcn_global_load_lds(
                (const __attribute__((address_space(1))) void*)gp,
                (__attribute__((address_space(3))) void*)&As[(i * 4 + w) * 512],
                16, 0, 0);
        }
#pragma unroll
        for (int i = 0; i < 8; ++i) {
            int lin = (i * 4 + w) * 64 + lane;
            int n = lin >> 3, slot = lin & 7, g = slot ^ (n & 7);
            const ushort* gp = W1c + (size_t)n * 512 + kc + g * 8;
            __builtin_amdgcn_global_load_lds(
                (const __attribute__((address_space(1))) void*)gp,
                (__attribute__((address_space(3))) void*)&Bs[(i * 4 + w) * 512],
                16, 0, 0);
        }
        __syncthreads();
#pragma unroll
        for (int ks = 0; ks < 2; ++ks) {
            const int K8 = ks * 4;
            short8 af[4], bf[4];
#pragma unroll
            for (int tr = 0; tr < 4; ++tr) {
                int r = tr * 16 + c15;
                af[tr] = *(const short8*)&As[r * 64 + (((K8 + quad) ^ (r & 7)) * 8)];
            }
#pragma unroll
            for (int tc = 0; tc < 4; ++tc) {
                int n = w * 64 + tc * 16 + c15;
                bf[tc] = *(const short8*)&Bs[n * 64 + (((K8 + quad) ^ (n & 7)) * 8)];
            }
#pragma unroll
            for (int tr = 0; tr < 4; ++tr)
#pragma unroll
                for (int tc = 0; tc < 4; ++tc)
                    acc[tr][tc] = __builtin_amdgcn_mfma_f32_16x16x32_bf16(
                        af[tr], bf[tc], acc[tr][tc], 0, 0, 0);
        }
        __syncthreads();
    }

    // ---- T1 tile -> Ts (bf16, 32-granule XOR swizzle per row) ----
#pragma unroll
    for (int tc = 0; tc < 4; ++tc) {
        int col = w * 64 + tc * 16 + c15;
        float bv = b1[c * 256 + col];
#pragma unroll
        for (int tr = 0; tr < 4; ++tr)
#pragma unroll
            for (int rg = 0; rg < 4; ++rg) {
                int row = tr * 16 + quad * 4 + rg;
                Ts[row * 256 + (((col >> 3) ^ (row & 31)) * 8) + (col & 7)]
                    = f2bf(fmaxf(acc[tr][tc][rg] + bv, 0.f));
            }
    }
    __syncthreads();

    // ---- Phase 2: L2 GEMM, K = 256 from Ts ----
#pragma unroll
    for (int i = 0; i < 4; ++i)
#pragma unroll
        for (int j = 0; j < 4; ++j)
#pragma unroll
            for (int r = 0; r < 4; ++r) acc[i][j][r] = 0.f;

    for (int kc = 0; kc < 256; kc += 64) {
#pragma unroll
        for (int i = 0; i < 8; ++i) {
            int lin = (i * 4 + w) * 64 + lane;
            int n = lin >> 3, slot = lin & 7, g = slot ^ (n & 7);
            const ushort* gp = W2c + (size_t)n * 256 + kc + g * 8;
            __builtin_amdgcn_global_load_lds(
                (const __attribute__((address_space(1))) void*)gp,
                (__attribute__((address_space(3))) void*)&Bs[(i * 4 + w) * 512],
                16, 0, 0);
        }
        __syncthreads();
#pragma unroll
        for (int ks = 0; ks < 2; ++ks) {
            short8 af[4], bf[4];
            const int g0 = (kc >> 3) + ks * 4 + quad;
#pragma unroll
            for (int tr = 0; tr < 4; ++tr) {
                int r = tr * 16 + c15;
                af[tr] = *(const short8*)&Ts[r * 256 + ((g0 ^ (r & 31)) * 8)];
            }
#pragma unroll
            for (int tc = 0; tc < 4; ++tc) {
                int n = w * 64 + tc * 16 + c15;
                bf[tc] = *(const short8*)&Bs[n * 64 + ((((ks * 4) + quad) ^ (n & 7)) * 8)];
            }
#pragma unroll
            for (int tr = 0; tr < 4; ++tr)
#pragma unroll
                for (int tc = 0; tc < 4; ++tc)
                    acc[tr][tc] = __builtin_amdgcn_mfma_f32_16x16x32_bf16(
                        af[tr], bf[tc], acc[tr][tc], 0, 0, 0);
        }
        __syncthreads();
    }

    // ---- Phase 3: relu(acc+b2) dot w3 ----
    float b2v[4], w3v[4];
#pragma unroll
    for (int tc = 0; tc < 4; ++tc) {
        int col = w * 64 + tc * 16 + c15;
        b2v[tc] = b2[c * 256 + col];
        w3v[tc] = w3[c * 256 + col];
    }
#pragma unroll
    for (int tr = 0; tr < 4; ++tr)
#pragma unroll
        for (int rg = 0; rg < 4; ++rg) {
            float p = 0.f;
#pragma unroll
            for (int tc = 0; tc < 4; ++tc)
                p += fmaxf(acc[tr][tc][rg] + b2v[tc], 0.f) * w3v[tc];
            p += __shfl_xor(p, 1);
            p += __shfl_xor(p, 2);
            p += __shfl_xor(p, 4);
            p += __shfl_xor(p, 8);
            if (c15 == 0) red[tr * 16 + quad * 4 + rg][w] = p;
        }
    __syncthreads();
    if (t < 64) {
        int grow = rowbase + t;
        if (grow < N) {
            float s = red[t][0] + red[t][1] + red[t][2] + red[t][3] + b3[c];
            out[(size_t)grow * NCH + c] = fmaxf(s, 0.f);
        }
    }
}

// ---------------------------------------------------------------------------
// Launch
// ---------------------------------------------------------------------------
extern "C" void kernel_launch(void* const* d_in, const int* in_sizes, int n_in,
                              void* d_out, int out_size, void* d_ws, size_t ws_size,
                              hipStream_t stream) {
    const float* x        = (const float*)d_in[0];
    const int*   eidx     = (const int*)d_in[1];
    const float* convW    = (const float*)d_in[2];
    const float* convB    = (const float*)d_in[3];
    const float* chanW1   = (const float*)d_in[4];
    const float* chanB1   = (const float*)d_in[5];
    const float* chanW2   = (const float*)d_in[6];
    const float* chanB2   = (const float*)d_in[7];
    const float* chanW3   = (const float*)d_in[8];
    const float* chanB3   = (const float*)d_in[9];
    float* out = (float*)d_out;

    const int N = in_sizes[0] / D;      // 100000
    const int E = in_sizes[1] / 2;      // 1600000
    const int* srcp = eidx;
    const int* dstp = eidx + E;
    const int nb = (N + 255) / 256;     // 391

    char* w = (char*)d_ws;
    auto take = [&](size_t bytes) {
        char* p = w;
        w += (bytes + 255) & ~(size_t)255;
        return p;
    };
    ushort* xb     = (ushort*)take((size_t)N * D * 2);
    ushort* h0     = (ushort*)take((size_t)N * D * 2);
    ushort* h1     = (ushort*)take((size_t)N * D * 2);
    ushort* h2     = (ushort*)take((size_t)N * D * 2);
    int*    deg    = (int*)take((size_t)N * 4);
    int*    offs   = (int*)take((size_t)(N + 1) * 4);
    int*    cursor = (int*)take((size_t)N * 4);
    int*    bsum   = (int*)take((size_t)nb * 4);
    int*    boff   = (int*)take((size_t)nb * 4);
    ushort* Wt1b   = (ushort*)take((size_t)NCH * 256 * 512 * 2);
    ushort* Wt2b   = (ushort*)take((size_t)NCH * 256 * 256 * 2);
    ushort* WtC    = (ushort*)take((size_t)NLAYER * 3 * D * D * 2);

    size_t used = (size_t)(w - (char*)d_ws);
    if (used > ws_size) return;
    size_t rem = ws_size - used;
    size_t need_gin = (((size_t)E * 4 + 255) & ~(size_t)255) + (size_t)N * D * 2;
    if (rem < need_gin) return;

    int*    csr = (int*)w;
    ushort* a   = (ushort*)(w + (((size_t)E * 4 + 255) & ~(size_t)255));

    // --- CSR build (XCD-partitioned hist + parallel scan + partitioned fill) ---
    hipMemsetAsync(deg, 0, (size_t)N * 4, stream);
    {
        int nchunks = (E + FILL_CHUNK - 1) / FILL_CHUNK;
        int nPer = (N + 7) / 8;
        hist_part_kernel<<<nchunks * 8, 256, 0, stream>>>(dstp, deg, E, nPer, N);
        blocksum_kernel<<<nb, 256, 0, stream>>>(deg, bsum, N);
        scanblk_kernel<<<1, 512, 0, stream>>>(bsum, boff, nb, offs, N, E);
        blockscan_kernel<<<nb, 256, 0, stream>>>(deg, boff, offs, cursor, N);
        fill_part_kernel<<<nchunks * 8, 256, 0, stream>>>(
            srcp, dstp, cursor, csr, E, nPer, N);
    }

    // --- converts (independent) ---
    cvtx_kernel<<<(N * 16 + 255) / 256, 256, 0, stream>>>(x, xb, N * 16);
    cvtW_kernel<<<dim3(512 / 32, 256 / 32, NCH), 256, 0, stream>>>(chanW1, Wt1b, 512, 256);
    cvtW_kernel<<<dim3(256 / 32, 256 / 32, NCH), 256, 0, stream>>>(chanW2, Wt2b, 256, 256);
    cvtW_kernel<<<dim3(D / 32, D / 32, NLAYER * 3), 256, 0, stream>>>(convW, WtC, D, D);

    const int rowtiles = (N + 127) / 128;
    const int aggblocks = (N * 16 + 255) / 256;      // 16 nodes per 256-thread block

    // --- GIN layers: agg + fused 3-linear MLP per layer ---
    ushort* hbuf[NLAYER] = {h0, h1, h2};
    const ushort* prev = xb;
    for (int l = 0; l < NLAYER; ++l) {
        agg_bf16<<<aggblocks, 256, 0, stream>>>(prev, offs, csr, a, N);
        gin_mlp_mfma<<<rowtiles, 256, 0, stream>>>(
            a, WtC + (size_t)l * 3 * D * D, convB + (size_t)l * 3 * D, hbuf[l], N);
        prev = hbuf[l];
    }

    // --- channel MLPs: fused, 64-row tiles, XCD-aware swizzled grid ---
    {
        const int T = (N + 63) / 64;          // 1563 row tiles
        const int chunkT = (T + 7) / 8;       // row tiles per XCD class
        const int grid = 8 * chunkT * NCH;
        chan_fused_mfma<<<grid, 256, 0, stream>>>(
            xb, h0, h1, h2,
            Wt1b, chanB1, Wt2b, chanB2, chanW3, chanB3,
            out, N, T, chunkT);
    }
}